// Round 1
// baseline (1270.122 us; speedup 1.0000x reference)
//
#include <hip/hip_runtime.h>
#include <hip/hip_bf16.h>

#define N_NODES 100000
#define N_EDGES 1600000
#define DIN 165
#define DHID 82
#define DH 128
#define DG 64

// ---------------- FeatureBooster: y = x * sigmoid(2 * (relu(x@w1)@w2)) ----------------
#define FB_M 8
__global__ __launch_bounds__(192) void fb_kernel(const float* __restrict__ x,
                                                 const float* __restrict__ w1,
                                                 const float* __restrict__ w2,
                                                 float* __restrict__ y) {
    __shared__ float xs[FB_M][DIN];
    __shared__ float hs[FB_M][DHID];
    int tid = threadIdx.x;
    int node0 = blockIdx.x * FB_M;
    for (int idx = tid; idx < FB_M * DIN; idx += 192) {
        int m = idx / DIN, f = idx % DIN;
        xs[m][f] = x[(long)(node0 + m) * DIN + f];
    }
    __syncthreads();
    if (tid < DHID) {
        float acc[FB_M];
#pragma unroll
        for (int m = 0; m < FB_M; m++) acc[m] = 0.f;
        for (int k = 0; k < DIN; k++) {
            float w = w1[k * DHID + tid];
#pragma unroll
            for (int m = 0; m < FB_M; m++) acc[m] += xs[m][k] * w;
        }
#pragma unroll
        for (int m = 0; m < FB_M; m++) hs[m][tid] = fmaxf(acc[m], 0.f);
    }
    __syncthreads();
    if (tid < DIN) {
        float acc[FB_M];
#pragma unroll
        for (int m = 0; m < FB_M; m++) acc[m] = 0.f;
        for (int k = 0; k < DHID; k++) {
            float w = w2[k * DIN + tid];
#pragma unroll
            for (int m = 0; m < FB_M; m++) acc[m] += hs[m][k] * w;
        }
#pragma unroll
        for (int m = 0; m < FB_M; m++) {
            float s = 1.f / (1.f + __expf(-2.f * acc[m]));
            y[(long)(node0 + m) * DIN + tid] = xs[m][tid] * s;
        }
    }
}

// ---------------- CSR build ----------------
__global__ void count_kernel(const int* __restrict__ dst, int* __restrict__ cnt) {
    int stride = gridDim.x * blockDim.x;
    for (int e = blockIdx.x * blockDim.x + threadIdx.x; e < N_EDGES; e += stride)
        atomicAdd(&cnt[dst[e]], 1);
}

__global__ __launch_bounds__(1024) void scan_kernel(const int* __restrict__ cnt,
                                                    int* __restrict__ rowptr) {
    __shared__ int buf[1024];
    __shared__ int carry_s;
    int tid = threadIdx.x;
    if (tid == 0) carry_s = 0;
    __syncthreads();
    for (int base = 0; base < N_NODES; base += 1024) {
        int i = base + tid;
        int v = (i < N_NODES) ? cnt[i] : 0;
        buf[tid] = v;
        __syncthreads();
        int xv = v;
        for (int off = 1; off < 1024; off <<= 1) {
            int t = (tid >= off) ? buf[tid - off] : 0;
            __syncthreads();
            xv += t;
            buf[tid] = xv;
            __syncthreads();
        }
        int carry = carry_s;
        if (i < N_NODES) rowptr[i] = carry + xv - v;  // exclusive
        __syncthreads();
        if (tid == 1023) carry_s = carry + buf[1023];
        __syncthreads();
    }
    if (tid == 0) rowptr[N_NODES] = carry_s;
}

__global__ void fill_kernel(const int* __restrict__ src, const int* __restrict__ dst,
                            const int* __restrict__ rowptr, int* __restrict__ fill,
                            int* __restrict__ esrc) {
    int stride = gridDim.x * blockDim.x;
    for (int e = blockIdx.x * blockDim.x + threadIdx.x; e < N_EDGES; e += stride) {
        int d = dst[e];
        int pos = rowptr[d] + atomicAdd(&fill[d], 1);
        esrc[pos] = src[e];
    }
}

// ---------------- SAGE: x2 = relu(mean_agg(y)@wl + bl + y@wr) ----------------
#define SG_M 8
__global__ __launch_bounds__(192) void sage_kernel(const float* __restrict__ y,
                                                   const int* __restrict__ rowptr,
                                                   const int* __restrict__ esrc,
                                                   const float* __restrict__ wl,
                                                   const float* __restrict__ bl,
                                                   const float* __restrict__ wr,
                                                   float* __restrict__ x2) {
    __shared__ float ys[SG_M][DIN];
    __shared__ float as[SG_M][DIN];
    int tid = threadIdx.x;
    int node0 = blockIdx.x * SG_M;
    for (int idx = tid; idx < SG_M * DIN; idx += 192) {
        int m = idx / DIN, f = idx % DIN;
        ys[m][f] = y[(long)(node0 + m) * DIN + f];
    }
    __syncthreads();
    for (int m = 0; m < SG_M; m++) {
        int i = node0 + m;
        int r0 = rowptr[i], r1 = rowptr[i + 1];
        if (tid < DIN) {
            float acc = 0.f;
            for (int e = r0; e < r1; e++) {
                int s = esrc[e];
                acc += y[(long)s * DIN + tid];
            }
            as[m][tid] = acc / fmaxf((float)(r1 - r0), 1.f);
        }
    }
    __syncthreads();
    if (tid < DH) {
        float acc[SG_M];
#pragma unroll
        for (int m = 0; m < SG_M; m++) acc[m] = bl[tid];
        for (int k = 0; k < DIN; k++) {
            float a = wl[k * DH + tid];
            float b = wr[k * DH + tid];
#pragma unroll
            for (int m = 0; m < SG_M; m++) acc[m] += as[m][k] * a + ys[m][k] * b;
        }
#pragma unroll
        for (int m = 0; m < SG_M; m++)
            x2[(long)(node0 + m) * DH + tid] = fmaxf(acc[m], 0.f);
    }
}

// ---------------- GAT projection: h = x2@gw, a_s = h@att_s, a_d = h@att_d ----------------
#define GH_M 8
__global__ __launch_bounds__(64) void gat_h_kernel(const float* __restrict__ x2,
                                                   const float* __restrict__ gw,
                                                   const float* __restrict__ att_s,
                                                   const float* __restrict__ att_d,
                                                   float* __restrict__ h,
                                                   float* __restrict__ a_s,
                                                   float* __restrict__ a_d) {
    __shared__ float xs[GH_M][DH];
    int tid = threadIdx.x;
    int node0 = blockIdx.x * GH_M;
    for (int idx = tid; idx < GH_M * DH; idx += 64) {
        int m = idx >> 7, f = idx & 127;
        xs[m][f] = x2[(long)(node0 + m) * DH + f];
    }
    __syncthreads();
    float acc[GH_M];
#pragma unroll
    for (int m = 0; m < GH_M; m++) acc[m] = 0.f;
    for (int k = 0; k < DH; k++) {
        float w = gw[k * DG + tid];
#pragma unroll
        for (int m = 0; m < GH_M; m++) acc[m] += xs[m][k] * w;
    }
    float vs_w = att_s[tid], vd_w = att_d[tid];
#pragma unroll
    for (int m = 0; m < GH_M; m++) {
        float hv = acc[m];
        h[(long)(node0 + m) * DG + tid] = hv;
        float vs = hv * vs_w, vd = hv * vd_w;
        for (int off = 32; off > 0; off >>= 1) {
            vs += __shfl_down(vs, off);
            vd += __shfl_down(vd, off);
        }
        if (tid == 0) {
            a_s[node0 + m] = vs;
            a_d[node0 + m] = vd;
        }
    }
}

// ---------------- GAT aggregate + bias + relu + Cheb(64->1) + sigmoid ----------------
__device__ __forceinline__ float leaky02(float v) { return v > 0.f ? v : 0.2f * v; }

__global__ __launch_bounds__(256) void gat_agg_kernel(const float* __restrict__ h,
                                                      const float* __restrict__ a_s,
                                                      const float* __restrict__ a_d,
                                                      const int* __restrict__ rowptr,
                                                      const int* __restrict__ esrc,
                                                      const float* __restrict__ gat_b,
                                                      const float* __restrict__ cheb_w,
                                                      const float* __restrict__ cheb_b,
                                                      float* __restrict__ out) {
    int wave = threadIdx.x >> 6;
    int lane = threadIdx.x & 63;
    int i = blockIdx.x * 4 + wave;
    if (i >= N_NODES) return;
    int r0 = rowptr[i], r1 = rowptr[i + 1];
    float adi = a_d[i];
    float asi = a_s[i];
    // pass 1: segment max (incl. self loop)
    float mx = leaky02(asi + adi);
    for (int e = r0 + lane; e < r1; e += 64)
        mx = fmaxf(mx, leaky02(a_s[esrc[e]] + adi));
    for (int off = 32; off > 0; off >>= 1) mx = fmaxf(mx, __shfl_down(mx, off));
    mx = __shfl(mx, 0);
    // pass 2: exp-weighted sum; lane owns feature=lane
    float s, acc;
    {
        float w = __expf(leaky02(asi + adi) - mx);
        s = w;
        acc = w * h[(long)i * DG + lane];
    }
    for (int e = r0; e < r1; e++) {
        int sn = esrc[e];
        float w = __expf(leaky02(a_s[sn] + adi) - mx);
        s += w;
        acc += w * h[(long)sn * DG + lane];
    }
    float o = fmaxf(acc / s + gat_b[lane], 0.f);
    float z = o * cheb_w[lane];
    for (int off = 32; off > 0; off >>= 1) z += __shfl_down(z, off);
    if (lane == 0) out[i] = 1.f / (1.f + __expf(-(z + cheb_b[0])));
}

extern "C" void kernel_launch(void* const* d_in, const int* in_sizes, int n_in,
                              void* d_out, int out_size, void* d_ws, size_t ws_size,
                              hipStream_t stream) {
    const float* x        = (const float*)d_in[0];
    const int*   eidx     = (const int*)d_in[1];   // [2, E] int32
    const float* fb_w1    = (const float*)d_in[2];
    const float* fb_w2    = (const float*)d_in[3];
    const float* sage_wl  = (const float*)d_in[4];
    const float* sage_bl  = (const float*)d_in[5];
    const float* sage_wr  = (const float*)d_in[6];
    const float* gat_w    = (const float*)d_in[7];
    const float* att_src  = (const float*)d_in[8];
    const float* att_dst  = (const float*)d_in[9];
    const float* gat_b    = (const float*)d_in[10];
    const float* cheb_w   = (const float*)d_in[11];
    const float* cheb_b   = (const float*)d_in[12];

    const int* src = eidx;
    const int* dst = eidx + N_EDGES;

    // workspace layout (~125 MB)
    float* y      = (float*)d_ws;                      // 16,500,000 floats (66 MB)
    float* x2     = y + 16500000;                      // 12,800,000 floats (51.2 MB)
    int*   rowptr = (int*)(x2 + 12800000);             // 100,001
    int*   cnt    = rowptr + (N_NODES + 1);            // 100,000
    int*   fill   = cnt + N_NODES;                     // 100,000 (contiguous with cnt)
    int*   esrc   = fill + N_NODES;                    // 1,600,000
    // h/a_s/a_d alias the dead y region (y unused after sage_kernel)
    float* h      = y;                                 // 6,400,000 floats
    float* a_s    = y + 6400000;                       // 100,000
    float* a_d    = a_s + N_NODES;                     // 100,000

    hipMemsetAsync(cnt, 0, 2 * N_NODES * sizeof(int), stream);

    fb_kernel<<<N_NODES / FB_M, 192, 0, stream>>>(x, fb_w1, fb_w2, y);
    count_kernel<<<1024, 256, 0, stream>>>(dst, cnt);
    scan_kernel<<<1, 1024, 0, stream>>>(cnt, rowptr);
    fill_kernel<<<1024, 256, 0, stream>>>(src, dst, rowptr, fill, esrc);
    sage_kernel<<<N_NODES / SG_M, 192, 0, stream>>>(y, rowptr, esrc, sage_wl, sage_bl,
                                                    sage_wr, x2);
    gat_h_kernel<<<N_NODES / GH_M, 64, 0, stream>>>(x2, gat_w, att_src, att_dst, h, a_s, a_d);
    gat_agg_kernel<<<N_NODES / 4, 256, 0, stream>>>(h, a_s, a_d, rowptr, esrc, gat_b,
                                                    cheb_w, cheb_b, (float*)d_out);
}

// Round 2
// 1075.754 us; speedup vs baseline: 1.1807x; 1.1807x over previous
//
#include <hip/hip_runtime.h>
#include <hip/hip_bf16.h>

#define N_NODES 100000
#define N_EDGES 1600000
#define DIN 165
#define DHID 82
#define DH 128
#define DG 64

// ============ fused FeatureBooster + SAGE linears ============
// y = x * sigmoid(2*(relu(x@w1)@w2))   (never materialized)
// t_l = y @ sage_wl                     [N,128] -> gathered later
// x2pre = y @ sage_wr + bl              [N,128] -> self part, finished in sage_agg
#define FBM 16
__global__ __launch_bounds__(256) void fb_lin_kernel(const float* __restrict__ x,
                                                     const float* __restrict__ w1,
                                                     const float* __restrict__ w2,
                                                     const float* __restrict__ wl,
                                                     const float* __restrict__ wr,
                                                     const float* __restrict__ bl,
                                                     float* __restrict__ t_l,
                                                     float* __restrict__ x2pre) {
    __shared__ float xs[FBM][DIN];   // 10560 B
    __shared__ float hs[FBM][DHID];  // 5248 B
    int tid = threadIdx.x;
    int node0 = blockIdx.x * FBM;
    for (int idx = tid; idx < FBM * DIN; idx += 256) {
        int m = idx / DIN, f = idx % DIN;
        xs[m][f] = x[(long)(node0 + m) * DIN + f];
    }
    __syncthreads();
    // stage 2: hidden = relu(x@w1), 82 cols x 2 node-halves
    if (tid < 2 * DHID) {
        int col, mh;
        if (tid < DHID) { col = tid; mh = 0; } else { col = tid - DHID; mh = 8; }
        float acc[8];
#pragma unroll
        for (int m = 0; m < 8; m++) acc[m] = 0.f;
        for (int k = 0; k < DIN; k++) {
            float w = w1[k * DHID + col];
#pragma unroll
            for (int m = 0; m < 8; m++) acc[m] += xs[mh + m][k] * w;
        }
#pragma unroll
        for (int m = 0; m < 8; m++) hs[mh + m][col] = fmaxf(acc[m], 0.f);
    }
    __syncthreads();
    // stage 3: y = x * sigmoid(2*(hidden@w2)), overwrite xs in place
    if (tid < DIN) {
        float acc[FBM];
#pragma unroll
        for (int m = 0; m < FBM; m++) acc[m] = 0.f;
        for (int k = 0; k < DHID; k++) {
            float w = w2[k * DIN + tid];
#pragma unroll
            for (int m = 0; m < FBM; m++) acc[m] += hs[m][k] * w;
        }
#pragma unroll
        for (int m = 0; m < FBM; m++) {
            float s = 1.f / (1.f + __expf(-2.f * acc[m]));
            xs[m][tid] *= s;
        }
    }
    __syncthreads();
    // stage 4: t_l = y@wl ; x2pre = y@wr + bl
    {
        int c = tid & 127;
        bool left = tid < 128;
        const float* w = left ? wl : wr;
        float init = left ? 0.f : bl[c];
        float acc[FBM];
#pragma unroll
        for (int m = 0; m < FBM; m++) acc[m] = init;
        for (int k = 0; k < DIN; k++) {
            float wv = w[k * DH + c];
#pragma unroll
            for (int m = 0; m < FBM; m++) acc[m] += xs[m][k] * wv;
        }
        float* outp = left ? t_l : x2pre;
#pragma unroll
        for (int m = 0; m < FBM; m++) outp[(long)(node0 + m) * DH + c] = acc[m];
    }
}

// ============ CSR build ============
__global__ void count_kernel(const int* __restrict__ dst, int* __restrict__ cnt) {
    int stride = gridDim.x * blockDim.x;
    for (int e = blockIdx.x * blockDim.x + threadIdx.x; e < N_EDGES; e += stride)
        atomicAdd(&cnt[dst[e]], 1);
}

__global__ __launch_bounds__(1024) void scan_kernel(const int* __restrict__ cnt,
                                                    int* __restrict__ rowptr) {
    __shared__ int wsum[16];
    __shared__ int carry_s;
    int tid = threadIdx.x, lane = tid & 63, wid = tid >> 6;
    if (tid == 0) carry_s = 0;
    __syncthreads();
    for (int base = 0; base < N_NODES; base += 1024) {
        int i = base + tid;
        int v = (i < N_NODES) ? cnt[i] : 0;
        int xv = v;
#pragma unroll
        for (int off = 1; off < 64; off <<= 1) {
            int t = __shfl_up(xv, off);
            if (lane >= off) xv += t;
        }
        if (lane == 63) wsum[wid] = xv;
        __syncthreads();
        if (wid == 0 && lane < 16) {
            int wv = wsum[lane];
#pragma unroll
            for (int off = 1; off < 16; off <<= 1) {
                int t = __shfl_up(wv, off);
                if (lane >= off) wv += t;
            }
            wsum[lane] = wv;
        }
        __syncthreads();
        int off0 = carry_s + (wid ? wsum[wid - 1] : 0);
        if (i < N_NODES) rowptr[i] = off0 + xv - v;  // exclusive
        __syncthreads();
        if (tid == 0) carry_s += wsum[15];
        __syncthreads();
    }
    if (tid == 0) rowptr[N_NODES] = carry_s;
}

__global__ void fill_kernel(const int* __restrict__ src, const int* __restrict__ dst,
                            const int* __restrict__ rowptr, int* __restrict__ fill,
                            int* __restrict__ esrc) {
    int stride = gridDim.x * blockDim.x;
    for (int e = blockIdx.x * blockDim.x + threadIdx.x; e < N_EDGES; e += stride) {
        int d = dst[e];
        int pos = rowptr[d] + atomicAdd(&fill[d], 1);
        esrc[pos] = src[e];
    }
}

// ============ SAGE aggregate: x2 = relu(x2pre + mean_edges(t_l[src])) ============
// one wave per node; lane owns 2 features (float2, 16B-aligned 512B rows)
__global__ __launch_bounds__(256) void sage_agg_kernel(const float* __restrict__ t_l,
                                                       const int* __restrict__ rowptr,
                                                       const int* __restrict__ esrc,
                                                       float* __restrict__ x2) {
    int wid = threadIdx.x >> 6, lane = threadIdx.x & 63;
    int i = blockIdx.x * 4 + wid;
    int r0 = rowptr[i], r1 = rowptr[i + 1];
    float2 acc = {0.f, 0.f};
    for (int e0 = r0; e0 < r1; e0 += 64) {
        int cnt = min(64, r1 - e0);
        int sn_v = (lane < cnt) ? esrc[e0 + lane] : 0;
        for (int j = 0; j < cnt; j++) {
            int sn = __shfl(sn_v, j);
            float2 vv = *((const float2*)(t_l + ((long)sn << 7)) + lane);
            acc.x += vv.x;
            acc.y += vv.y;
        }
    }
    float inv = 1.f / fmaxf((float)(r1 - r0), 1.f);
    float2* xp = (float2*)(x2 + ((long)i << 7)) + lane;
    float2 pre = *xp;
    float2 o;
    o.x = fmaxf(pre.x + acc.x * inv, 0.f);
    o.y = fmaxf(pre.y + acc.y * inv, 0.f);
    *xp = o;
}

// ============ GAT projection: h = x2@gw, a_s = h@att_s, a_d = h@att_d ============
#define GH_M 8
__global__ __launch_bounds__(64) void gat_h_kernel(const float* __restrict__ x2,
                                                   const float* __restrict__ gw,
                                                   const float* __restrict__ att_s,
                                                   const float* __restrict__ att_d,
                                                   float* __restrict__ h,
                                                   float* __restrict__ a_s,
                                                   float* __restrict__ a_d) {
    __shared__ float xs[GH_M][DH];
    int tid = threadIdx.x;
    int node0 = blockIdx.x * GH_M;
    for (int idx = tid; idx < GH_M * DH; idx += 64) {
        int m = idx >> 7, f = idx & 127;
        xs[m][f] = x2[(long)(node0 + m) * DH + f];
    }
    __syncthreads();
    float acc[GH_M];
#pragma unroll
    for (int m = 0; m < GH_M; m++) acc[m] = 0.f;
    for (int k = 0; k < DH; k++) {
        float w = gw[k * DG + tid];
#pragma unroll
        for (int m = 0; m < GH_M; m++) acc[m] += xs[m][k] * w;
    }
    float vs_w = att_s[tid], vd_w = att_d[tid];
#pragma unroll
    for (int m = 0; m < GH_M; m++) {
        float hv = acc[m];
        h[(long)(node0 + m) * DG + tid] = hv;
        float vs = hv * vs_w, vd = hv * vd_w;
        for (int off = 32; off > 0; off >>= 1) {
            vs += __shfl_down(vs, off);
            vd += __shfl_down(vd, off);
        }
        if (tid == 0) {
            a_s[node0 + m] = vs;
            a_d[node0 + m] = vd;
        }
    }
}

// ============ GAT aggregate + bias + relu + Cheb(64->1) + sigmoid ============
__device__ __forceinline__ float leaky02(float v) { return v > 0.f ? v : 0.2f * v; }

__global__ __launch_bounds__(256) void gat_agg_kernel(const float* __restrict__ h,
                                                      const float* __restrict__ a_s,
                                                      const float* __restrict__ a_d,
                                                      const int* __restrict__ rowptr,
                                                      const int* __restrict__ esrc,
                                                      const float* __restrict__ gat_b,
                                                      const float* __restrict__ cheb_w,
                                                      const float* __restrict__ cheb_b,
                                                      float* __restrict__ out) {
    int wid = threadIdx.x >> 6, lane = threadIdx.x & 63;
    int i = blockIdx.x * 4 + wid;
    int r0 = rowptr[i], r1 = rowptr[i + 1];
    float adi = a_d[i], asi = a_s[i];
    // pass 1: segment max (lane-parallel over edges, incl. self loop)
    float mx = leaky02(asi + adi);
    for (int e = r0 + lane; e < r1; e += 64)
        mx = fmaxf(mx, leaky02(a_s[esrc[e]] + adi));
#pragma unroll
    for (int off = 32; off > 0; off >>= 1) mx = fmaxf(mx, __shfl_xor(mx, off));
    // pass 2: weighted sum; lane owns feature=lane; 64-edge shuffle chunks
    float ws = __expf(leaky02(asi + adi) - mx);
    float s = ws;
    float acc = ws * h[((long)i << 6) + lane];
    for (int e0 = r0; e0 < r1; e0 += 64) {
        int cnt = min(64, r1 - e0);
        int sn_v = (lane < cnt) ? esrc[e0 + lane] : 0;
        float av = (lane < cnt) ? a_s[sn_v] : 0.f;
        for (int j = 0; j < cnt; j++) {
            int sn = __shfl(sn_v, j);
            float w = __expf(leaky02(__shfl(av, j) + adi) - mx);
            s += w;
            acc += w * h[((long)sn << 6) + lane];
        }
    }
    float o = fmaxf(acc / s + gat_b[lane], 0.f);
    float z = o * cheb_w[lane];
#pragma unroll
    for (int off = 32; off > 0; off >>= 1) z += __shfl_down(z, off);
    if (lane == 0) out[i] = 1.f / (1.f + __expf(-(z + cheb_b[0])));
}

extern "C" void kernel_launch(void* const* d_in, const int* in_sizes, int n_in,
                              void* d_out, int out_size, void* d_ws, size_t ws_size,
                              hipStream_t stream) {
    const float* x        = (const float*)d_in[0];
    const int*   eidx     = (const int*)d_in[1];   // [2, E]
    const float* fb_w1    = (const float*)d_in[2];
    const float* fb_w2    = (const float*)d_in[3];
    const float* sage_wl  = (const float*)d_in[4];
    const float* sage_bl  = (const float*)d_in[5];
    const float* sage_wr  = (const float*)d_in[6];
    const float* gat_w    = (const float*)d_in[7];
    const float* att_src  = (const float*)d_in[8];
    const float* att_dst  = (const float*)d_in[9];
    const float* gat_b    = (const float*)d_in[10];
    const float* cheb_w   = (const float*)d_in[11];
    const float* cheb_b   = (const float*)d_in[12];

    const int* src = eidx;
    const int* dst = eidx + N_EDGES;

    // workspace (~110 MB, fits proven 125 MB)
    float* t_l    = (float*)d_ws;                  // 12.8M floats (51.2 MB)
    float* x2     = t_l + 12800000;                // 12.8M floats (51.2 MB)
    int*   rowptr = (int*)(x2 + 12800000);         // 100,001
    int*   cnt    = rowptr + (N_NODES + 1);        // 100,000
    int*   fill   = cnt + N_NODES;                 // 100,000
    int*   esrc   = fill + N_NODES;                // 1,600,000
    // t_l dead after sage_agg -> alias gat buffers over it
    float* h      = t_l;                           // 6.4M floats
    float* a_s    = t_l + 6400000;                 // 100,000
    float* a_d    = a_s + N_NODES;                 // 100,000

    hipMemsetAsync(cnt, 0, 2 * N_NODES * sizeof(int), stream);

    count_kernel<<<1024, 256, 0, stream>>>(dst, cnt);
    scan_kernel<<<1, 1024, 0, stream>>>(cnt, rowptr);
    fill_kernel<<<1024, 256, 0, stream>>>(src, dst, rowptr, fill, esrc);
    fb_lin_kernel<<<N_NODES / FBM, 256, 0, stream>>>(x, fb_w1, fb_w2, sage_wl, sage_wr,
                                                     sage_bl, t_l, x2);
    sage_agg_kernel<<<N_NODES / 4, 256, 0, stream>>>(t_l, rowptr, esrc, x2);
    gat_h_kernel<<<N_NODES / GH_M, 64, 0, stream>>>(x2, gat_w, att_src, att_dst, h, a_s, a_d);
    gat_agg_kernel<<<N_NODES / 4, 256, 0, stream>>>(h, a_s, a_d, rowptr, esrc, gat_b,
                                                    cheb_w, cheb_b, (float*)d_out);
}

// Round 3
// 826.782 us; speedup vs baseline: 1.5362x; 1.3011x over previous
//
#include <hip/hip_runtime.h>
#include <hip/hip_bf16.h>

#define N_NODES 100000
#define N_EDGES 1600000
#define DIN 165
#define DHID 82
#define DH 128
#define DG 64

typedef _Float16 f16;
typedef f16 f16x8 __attribute__((ext_vector_type(8)));
typedef f16 f16x2 __attribute__((ext_vector_type(2)));
typedef float f32x4 __attribute__((ext_vector_type(4)));

#define MFMA16(a, b, c) __builtin_amdgcn_mfma_f32_16x16x32_f16(a, b, c, 0, 0, 0)

// MFMA 16x16x32 fragment layouts (verified per guide m89/m120):
//   A[m][k]: m = lane&15, k = (lane>>4)*8 + j   (8 contiguous k per lane)
//   B[k][n]: n = lane&15, k = (lane>>4)*8 + j
//   D[m][n]: n = lane&15, m = (lane>>4)*4 + reg

// ============ K1: fused FeatureBooster -> Y f16 [N][192] (k-pad zeroed) ============
// H = relu(X@W1) ; M2 = H@W2 ; Y = X * sigmoid(2*M2)
__global__ __launch_bounds__(256) void fb_y_kernel(const float* __restrict__ x,
                                                   const float* __restrict__ w1,
                                                   const float* __restrict__ w2,
                                                   f16* __restrict__ Y) {
    __shared__ f16 wt1[96 * 200];       // W1^T [n][k], n-pad + k-pad zeroed  (38.4 KB)
    __shared__ f16 wt2[192 * 104];      // W2^T [n][k], k-pad zeroed          (39.9 KB)
    __shared__ f16 hb[2][16 * 104];     // H tile per wave-pair               (6.7 KB)
    int tid = threadIdx.x;
    // stage weights once per block (transposed, f16)
    for (int idx = tid; idx < 96 * 200; idx += 256) {
        int n = idx / 200, k = idx % 200;
        wt1[idx] = (f16)((n < DHID && k < DIN) ? w1[k * DHID + n] : 0.f);
    }
    for (int idx = tid; idx < 192 * 104; idx += 256) {
        int n = idx / 104, k = idx % 104;
        wt2[idx] = (f16)((n < DIN && k < DHID) ? w2[k * DIN + n] : 0.f);
    }
    __syncthreads();
    int wave = tid >> 6, lane = tid & 63;
    int pair = wave >> 1, sub = wave & 1;
    int q = lane >> 4, l16 = lane & 15;
    // 6250 m-tiles over grid=625 blocks x 2 pairs => exactly 5 iters per pair (barrier-uniform)
    for (int mt = blockIdx.x * 2 + pair; mt < 6250; mt += 1250) {
        int node0 = mt * 16;
        // ---- stage 1: wave handles n-tiles sub*3 .. sub*3+2 (H cols) ----
        f32x4 acc1[3];
#pragma unroll
        for (int t = 0; t < 3; t++) acc1[t] = (f32x4){0.f, 0.f, 0.f, 0.f};
        const float* xrow = x + (long)(node0 + l16) * DIN;
#pragma unroll
        for (int ks = 0; ks < 6; ks++) {
            int kb = ks * 32 + q * 8;
            f16x8 a;
#pragma unroll
            for (int j = 0; j < 8; j++) {
                int k = kb + j;
                a[j] = (f16)((k < DIN) ? xrow[k] : 0.f);
            }
#pragma unroll
            for (int t = 0; t < 3; t++) {
                int n0 = (sub * 3 + t) * 16;
                f16x8 b = *((const f16x8*)&wt1[(n0 + l16) * 200 + kb]);
                acc1[t] = MFMA16(a, b, acc1[t]);
            }
        }
#pragma unroll
        for (int t = 0; t < 3; t++) {
            int n0 = (sub * 3 + t) * 16;
#pragma unroll
            for (int r = 0; r < 4; r++) {
                int m = q * 4 + r;
                hb[pair][m * 104 + n0 + l16] = (f16)fmaxf(acc1[t][r], 0.f);
            }
        }
        __syncthreads();
        // ---- stage 2: wave handles n-tiles sub*6 .. sub*6+5 (Y cols), K=96 ----
        f32x4 acc2[6];
#pragma unroll
        for (int t = 0; t < 6; t++) acc2[t] = (f32x4){0.f, 0.f, 0.f, 0.f};
#pragma unroll
        for (int ks = 0; ks < 3; ks++) {
            int kb = ks * 32 + q * 8;
            f16x8 a = *((const f16x8*)&hb[pair][l16 * 104 + kb]);
#pragma unroll
            for (int t = 0; t < 6; t++) {
                int n0 = (sub * 6 + t) * 16;
                f16x8 b = *((const f16x8*)&wt2[(n0 + l16) * 104 + kb]);
                acc2[t] = MFMA16(a, b, acc2[t]);
            }
        }
        __syncthreads();  // protect hb for next iteration
        // ---- stage 3: Y = x * sigmoid(2*M2) ----
#pragma unroll
        for (int t = 0; t < 6; t++) {
            int n = (sub * 6 + t) * 16 + l16;
            if (n < DIN) {
#pragma unroll
                for (int r = 0; r < 4; r++) {
                    int node = node0 + q * 4 + r;
                    float g = 1.f / (1.f + __expf(-2.f * acc2[t][r]));
                    float xv = x[(long)node * DIN + n];
                    Y[(long)node * 192 + n] = (f16)(xv * g);
                }
            }
        }
    }
}

// ============ K2: t_l = Y@WL (f16 out) ; x2pre = Y@WR + bl (f32 out) ============
// B-frags in VGPRs (24 frags), A streamed from global Y. grid = (gx, 4 col-groups).
__global__ __launch_bounds__(256) void sage_lin_kernel(const f16* __restrict__ Y,
                                                       const float* __restrict__ wl,
                                                       const float* __restrict__ wr,
                                                       const float* __restrict__ bl,
                                                       f16* __restrict__ t_l,
                                                       float* __restrict__ x2) {
    int tid = threadIdx.x, wave = tid >> 6, lane = tid & 63;
    int q = lane >> 4, l16 = lane & 15;
    int g = blockIdx.y;  // 0,1 -> WL ; 2,3 -> WR
    bool isR = (g >= 2);
    const float* W = isR ? wr : wl;
    int cbase = (g & 1) * 64;
    f16x8 bf[4][6];
    float blv[4];
#pragma unroll
    for (int nt = 0; nt < 4; nt++) {
        int col = cbase + nt * 16 + l16;
        blv[nt] = isR ? bl[col] : 0.f;
#pragma unroll
        for (int ks = 0; ks < 6; ks++) {
            int kb = ks * 32 + q * 8;
            f16x8 b;
#pragma unroll
            for (int j = 0; j < 8; j++) {
                int k = kb + j;
                b[j] = (f16)((k < DIN) ? W[k * DH + col] : 0.f);
            }
            bf[nt][ks] = b;
        }
    }
    int stride = gridDim.x * 4;
    for (int mt = blockIdx.x * 4 + wave; mt < 6250; mt += stride) {
        const f16* yrow = Y + (long)(mt * 16 + l16) * 192;
        f32x4 acc[4];
#pragma unroll
        for (int nt = 0; nt < 4; nt++) acc[nt] = (f32x4){0.f, 0.f, 0.f, 0.f};
#pragma unroll
        for (int ks = 0; ks < 6; ks++) {
            f16x8 a = *((const f16x8*)(yrow + ks * 32 + q * 8));
#pragma unroll
            for (int nt = 0; nt < 4; nt++) acc[nt] = MFMA16(a, bf[nt][ks], acc[nt]);
        }
#pragma unroll
        for (int nt = 0; nt < 4; nt++) {
            int col = cbase + nt * 16 + l16;
#pragma unroll
            for (int r = 0; r < 4; r++) {
                int node = mt * 16 + q * 4 + r;
                if (isR)
                    x2[(long)node * DH + col] = acc[nt][r] + blv[nt];
                else
                    t_l[(long)node * DH + col] = (f16)acc[nt][r];
            }
        }
    }
}

// ============ CSR build ============
__global__ void count_kernel(const int* __restrict__ dst, int* __restrict__ cnt) {
    int stride = gridDim.x * blockDim.x;
    for (int e = blockIdx.x * blockDim.x + threadIdx.x; e < N_EDGES; e += stride)
        atomicAdd(&cnt[dst[e]], 1);
}

__global__ __launch_bounds__(1024) void scan_kernel(const int* __restrict__ cnt,
                                                    int* __restrict__ rowptr) {
    __shared__ int wsum[16];
    __shared__ int carry_s;
    int tid = threadIdx.x, lane = tid & 63, wid = tid >> 6;
    if (tid == 0) carry_s = 0;
    __syncthreads();
    for (int base = 0; base < N_NODES; base += 1024) {
        int i = base + tid;
        int v = (i < N_NODES) ? cnt[i] : 0;
        int xv = v;
#pragma unroll
        for (int off = 1; off < 64; off <<= 1) {
            int t = __shfl_up(xv, off);
            if (lane >= off) xv += t;
        }
        if (lane == 63) wsum[wid] = xv;
        __syncthreads();
        if (wid == 0 && lane < 16) {
            int wv = wsum[lane];
#pragma unroll
            for (int off = 1; off < 16; off <<= 1) {
                int t = __shfl_up(wv, off);
                if (lane >= off) wv += t;
            }
            wsum[lane] = wv;
        }
        __syncthreads();
        int off0 = carry_s + (wid ? wsum[wid - 1] : 0);
        if (i < N_NODES) rowptr[i] = off0 + xv - v;
        __syncthreads();
        if (tid == 0) carry_s += wsum[15];
        __syncthreads();
    }
    if (tid == 0) rowptr[N_NODES] = carry_s;
}

__global__ void fill_kernel(const int* __restrict__ src, const int* __restrict__ dst,
                            const int* __restrict__ rowptr, int* __restrict__ fill,
                            int* __restrict__ esrc) {
    int stride = gridDim.x * blockDim.x;
    for (int e = blockIdx.x * blockDim.x + threadIdx.x; e < N_EDGES; e += stride) {
        int d = dst[e];
        int pos = rowptr[d] + atomicAdd(&fill[d], 1);
        esrc[pos] = src[e];
    }
}

// ============ SAGE aggregate: x2 = relu(x2pre + mean(t_l[src])) ============
__global__ __launch_bounds__(256) void sage_agg_kernel(const f16* __restrict__ t_l,
                                                       const int* __restrict__ rowptr,
                                                       const int* __restrict__ esrc,
                                                       float* __restrict__ x2) {
    int wid = threadIdx.x >> 6, lane = threadIdx.x & 63;
    int i = blockIdx.x * 4 + wid;
    int r0 = rowptr[i], r1 = rowptr[i + 1];
    float ax = 0.f, ay = 0.f;
    for (int e0 = r0; e0 < r1; e0 += 64) {
        int cnt = min(64, r1 - e0);
        int sn_v = (lane < cnt) ? esrc[e0 + lane] : 0;
        for (int j = 0; j < cnt; j++) {
            int sn = __shfl(sn_v, j);
            f16x2 p = *((const f16x2*)(t_l + (long)sn * DH) + lane);
            ax += (float)p.x;
            ay += (float)p.y;
        }
    }
    float inv = 1.f / fmaxf((float)(r1 - r0), 1.f);
    float2* xp = (float2*)(x2 + (long)i * DH) + lane;
    float2 pre = *xp;
    float2 o;
    o.x = fmaxf(pre.x + ax * inv, 0.f);
    o.y = fmaxf(pre.y + ay * inv, 0.f);
    *xp = o;
}

// ============ K3: h = x2@gw (f16 out), a_s = h@att_s, a_d = h@att_d ============
__global__ __launch_bounds__(256) void gat_h_kernel(const float* __restrict__ x2,
                                                    const float* __restrict__ gw,
                                                    const float* __restrict__ att_s_w,
                                                    const float* __restrict__ att_d_w,
                                                    f16* __restrict__ h,
                                                    float* __restrict__ a_s,
                                                    float* __restrict__ a_d) {
    int tid = threadIdx.x, wave = tid >> 6, lane = tid & 63;
    int q = lane >> 4, l16 = lane & 15;
    f16x8 bf[4][4];
    float asw[4], adw[4];
#pragma unroll
    for (int nt = 0; nt < 4; nt++) {
        int col = nt * 16 + l16;
        asw[nt] = att_s_w[col];
        adw[nt] = att_d_w[col];
#pragma unroll
        for (int ks = 0; ks < 4; ks++) {
            int kb = ks * 32 + q * 8;
            f16x8 b;
#pragma unroll
            for (int j = 0; j < 8; j++) b[j] = (f16)gw[(kb + j) * DG + col];
            bf[nt][ks] = b;
        }
    }
    int stride = gridDim.x * 4;
    for (int mt = blockIdx.x * 4 + wave; mt < 6250; mt += stride) {
        const float* xr = x2 + (long)(mt * 16 + l16) * DH;
        f32x4 acc[4];
#pragma unroll
        for (int nt = 0; nt < 4; nt++) acc[nt] = (f32x4){0.f, 0.f, 0.f, 0.f};
#pragma unroll
        for (int ks = 0; ks < 4; ks++) {
            int kb = ks * 32 + q * 8;
            f16x8 a;
#pragma unroll
            for (int j = 0; j < 8; j++) a[j] = (f16)xr[kb + j];
#pragma unroll
            for (int nt = 0; nt < 4; nt++) acc[nt] = MFMA16(a, bf[nt][ks], acc[nt]);
        }
#pragma unroll
        for (int r = 0; r < 4; r++) {
            int node = mt * 16 + q * 4 + r;
            float vs = 0.f, vd = 0.f;
#pragma unroll
            for (int nt = 0; nt < 4; nt++) {
                float hv = acc[nt][r];
                h[(long)node * DG + nt * 16 + l16] = (f16)hv;
                vs += hv * asw[nt];
                vd += hv * adw[nt];
            }
#pragma unroll
            for (int off = 1; off < 16; off <<= 1) {
                vs += __shfl_xor(vs, off);
                vd += __shfl_xor(vd, off);
            }
            if (l16 == 0) {
                a_s[node] = vs;
                a_d[node] = vd;
            }
        }
    }
}

// ============ GAT aggregate + bias + relu + Cheb(64->1) + sigmoid ============
__device__ __forceinline__ float leaky02(float v) { return v > 0.f ? v : 0.2f * v; }

__global__ __launch_bounds__(256) void gat_agg_kernel(const f16* __restrict__ h,
                                                      const float* __restrict__ a_s,
                                                      const float* __restrict__ a_d,
                                                      const int* __restrict__ rowptr,
                                                      const int* __restrict__ esrc,
                                                      const float* __restrict__ gat_b,
                                                      const float* __restrict__ cheb_w,
                                                      const float* __restrict__ cheb_b,
                                                      float* __restrict__ out) {
    int wid = threadIdx.x >> 6, lane = threadIdx.x & 63;
    int i = blockIdx.x * 4 + wid;
    int r0 = rowptr[i], r1 = rowptr[i + 1];
    float adi = a_d[i], asi = a_s[i];
    float mx = leaky02(asi + adi);
    for (int e = r0 + lane; e < r1; e += 64)
        mx = fmaxf(mx, leaky02(a_s[esrc[e]] + adi));
#pragma unroll
    for (int off = 32; off > 0; off >>= 1) mx = fmaxf(mx, __shfl_xor(mx, off));
    float ws = __expf(leaky02(asi + adi) - mx);
    float s = ws;
    float acc = ws * (float)h[(long)i * DG + lane];
    for (int e0 = r0; e0 < r1; e0 += 64) {
        int cnt = min(64, r1 - e0);
        int sn_v = (lane < cnt) ? esrc[e0 + lane] : 0;
        float av = (lane < cnt) ? a_s[sn_v] : 0.f;
        for (int j = 0; j < cnt; j++) {
            int sn = __shfl(sn_v, j);
            float w = __expf(leaky02(__shfl(av, j) + adi) - mx);
            s += w;
            acc += w * (float)h[(long)sn * DG + lane];
        }
    }
    float o = fmaxf(acc / s + gat_b[lane], 0.f);
    float z = o * cheb_w[lane];
#pragma unroll
    for (int off = 32; off > 0; off >>= 1) z += __shfl_down(z, off);
    if (lane == 0) out[i] = 1.f / (1.f + __expf(-(z + cheb_b[0])));
}

extern "C" void kernel_launch(void* const* d_in, const int* in_sizes, int n_in,
                              void* d_out, int out_size, void* d_ws, size_t ws_size,
                              hipStream_t stream) {
    const float* x       = (const float*)d_in[0];
    const int*   eidx    = (const int*)d_in[1];
    const float* fb_w1   = (const float*)d_in[2];
    const float* fb_w2   = (const float*)d_in[3];
    const float* sage_wl = (const float*)d_in[4];
    const float* sage_bl = (const float*)d_in[5];
    const float* sage_wr = (const float*)d_in[6];
    const float* gat_w   = (const float*)d_in[7];
    const float* att_src = (const float*)d_in[8];
    const float* att_dst = (const float*)d_in[9];
    const float* gat_b   = (const float*)d_in[10];
    const float* cheb_w  = (const float*)d_in[11];
    const float* cheb_b  = (const float*)d_in[12];

    const int* src = eidx;
    const int* dst = eidx + N_EDGES;

    // workspace layout (~123 MB)
    char* p = (char*)d_ws;
    f16* Y = (f16*)p;        p += (long)N_NODES * 192 * sizeof(f16);   // 38.4 MB
    f16* t_l = (f16*)p;      p += (long)N_NODES * DH * sizeof(f16);    // 25.6 MB
    float* x2 = (float*)p;   p += (long)N_NODES * DH * sizeof(float);  // 51.2 MB
    int* rowptr = (int*)p;   p += (N_NODES + 1) * sizeof(int);
    int* cnt = (int*)p;      p += N_NODES * sizeof(int);
    int* fill = (int*)p;     p += N_NODES * sizeof(int);
    int* esrc = (int*)p;     p += (long)N_EDGES * sizeof(int);
    // h/a_s/a_d alias Y (dead after sage_lin)
    f16* h = Y;                                              // 12.8 MB
    float* a_s = (float*)((char*)Y + (long)N_NODES * DG * sizeof(f16));
    float* a_d = a_s + N_NODES;

    hipMemsetAsync(cnt, 0, 2 * N_NODES * sizeof(int), stream);          // cnt + fill
    hipMemsetAsync(Y, 0, (long)N_NODES * 192 * sizeof(f16), stream);    // Y k-pad zeros

    count_kernel<<<1024, 256, 0, stream>>>(dst, cnt);
    scan_kernel<<<1, 1024, 0, stream>>>(cnt, rowptr);
    fill_kernel<<<1024, 256, 0, stream>>>(src, dst, rowptr, fill, esrc);
    fb_y_kernel<<<625, 256, 0, stream>>>(x, fb_w1, fb_w2, Y);
    sage_lin_kernel<<<dim3(196, 4), 256, 0, stream>>>(Y, sage_wl, sage_wr, sage_bl, t_l, x2);
    sage_agg_kernel<<<N_NODES / 4, 256, 0, stream>>>(t_l, rowptr, esrc, x2);
    gat_h_kernel<<<392, 256, 0, stream>>>(x2, gat_w, att_src, att_dst, h, a_s, a_d);
    gat_agg_kernel<<<N_NODES / 4, 256, 0, stream>>>(h, a_s, a_d, rowptr, esrc, gat_b,
                                                    cheb_w, cheb_b, (float*)d_out);
}

// Round 4
// 765.801 us; speedup vs baseline: 1.6586x; 1.0796x over previous
//
#include <hip/hip_runtime.h>
#include <hip/hip_bf16.h>

#define N_NODES 100000
#define N_EDGES 1600000
#define DIN 165
#define DHID 82
#define DH 128
#define DG 64

typedef _Float16 f16;
typedef f16 f16x8 __attribute__((ext_vector_type(8)));
typedef f16 f16x4 __attribute__((ext_vector_type(4)));
typedef f16 f16x2 __attribute__((ext_vector_type(2)));
typedef float f32x4 __attribute__((ext_vector_type(4)));

#define MFMA16(a, b, c) __builtin_amdgcn_mfma_f32_16x16x32_f16(a, b, c, 0, 0, 0)

// MFMA 16x16x32 fragment layouts (verified, guide m89/m120):
//   A[m][k]: m = lane&15, k = (lane>>4)*8 + j
//   B[k][n]: n = lane&15, k = (lane>>4)*8 + j
//   D[m][n]: n = lane&15, m = (lane>>4)*4 + reg

// ============ K0: Xp[N,192] f16 = pad(X) ============
__global__ __launch_bounds__(256) void xpad_kernel(const float* __restrict__ x,
                                                   f16* __restrict__ Xp) {
    int gid = blockIdx.x * 256 + threadIdx.x;   // one thread per 4 cols
    int node = gid / 48, g = gid % 48;
    int col0 = g * 4;
    f16x4 o;
#pragma unroll
    for (int j = 0; j < 4; j++) {
        int c = col0 + j;
        o[j] = (f16)((c < DIN) ? x[(long)node * DIN + c] : 0.f);
    }
    *((f16x4*)(Xp + (long)node * 192 + col0)) = o;
}

// ============ K1: H[N,96] f16 = relu(Xp @ W1pad) ============
// B-frags in VGPRs (3 n-tiles x 6 k-steps = 18 frags), grid.y=2 col-split
__global__ __launch_bounds__(256) void h_kernel(const f16* __restrict__ Xp,
                                                const float* __restrict__ w1,
                                                f16* __restrict__ H) {
    int tid = threadIdx.x, wave = tid >> 6, lane = tid & 63;
    int q = lane >> 4, l16 = lane & 15;
    int nbase = blockIdx.y * 48;
    f16x8 bf[3][6];
#pragma unroll
    for (int nt = 0; nt < 3; nt++) {
        int col = nbase + nt * 16 + l16;
#pragma unroll
        for (int ks = 0; ks < 6; ks++) {
            int kb = ks * 32 + q * 8;
            f16x8 b;
#pragma unroll
            for (int j = 0; j < 8; j++) {
                int k = kb + j;
                b[j] = (f16)((k < DIN && col < DHID) ? w1[k * DHID + col] : 0.f);
            }
            bf[nt][ks] = b;
        }
    }
    int stride = gridDim.x * 4;
    for (int mt = blockIdx.x * 4 + wave; mt < 6250; mt += stride) {
        const f16* xr = Xp + (long)(mt * 16 + l16) * 192;
        f32x4 acc[3];
#pragma unroll
        for (int nt = 0; nt < 3; nt++) acc[nt] = (f32x4){0.f, 0.f, 0.f, 0.f};
#pragma unroll
        for (int ks = 0; ks < 6; ks++) {
            f16x8 a = *((const f16x8*)(xr + ks * 32 + q * 8));
#pragma unroll
            for (int nt = 0; nt < 3; nt++) acc[nt] = MFMA16(a, bf[nt][ks], acc[nt]);
        }
#pragma unroll
        for (int nt = 0; nt < 3; nt++) {
            int col = nbase + nt * 16 + l16;
#pragma unroll
            for (int r = 0; r < 4; r++) {
                int node = mt * 16 + q * 4 + r;
                H[(long)node * 96 + col] = (f16)fmaxf(acc[nt][r], 0.f);
            }
        }
    }
}

// ============ K2: Y[N,192] f16 = Xp * sigmoid(2*(H @ W2pad)) ============
// 3 n-tiles x 3 k-steps = 9 B-frags, grid.y=4 col-split
__global__ __launch_bounds__(256) void y_kernel(const f16* __restrict__ Xp,
                                                const f16* __restrict__ H,
                                                const float* __restrict__ w2,
                                                f16* __restrict__ Y) {
    int tid = threadIdx.x, wave = tid >> 6, lane = tid & 63;
    int q = lane >> 4, l16 = lane & 15;
    int nbase = blockIdx.y * 48;
    f16x8 bf[3][3];
#pragma unroll
    for (int nt = 0; nt < 3; nt++) {
        int col = nbase + nt * 16 + l16;
#pragma unroll
        for (int ks = 0; ks < 3; ks++) {
            int kb = ks * 32 + q * 8;
            f16x8 b;
#pragma unroll
            for (int j = 0; j < 8; j++) {
                int k = kb + j;
                b[j] = (f16)((k < DHID && col < DIN) ? w2[k * DIN + col] : 0.f);
            }
            bf[nt][ks] = b;
        }
    }
    int stride = gridDim.x * 4;
    for (int mt = blockIdx.x * 4 + wave; mt < 6250; mt += stride) {
        const f16* hr = H + (long)(mt * 16 + l16) * 96;
        f32x4 acc[3];
#pragma unroll
        for (int nt = 0; nt < 3; nt++) acc[nt] = (f32x4){0.f, 0.f, 0.f, 0.f};
#pragma unroll
        for (int ks = 0; ks < 3; ks++) {
            f16x8 a = *((const f16x8*)(hr + ks * 32 + q * 8));
#pragma unroll
            for (int nt = 0; nt < 3; nt++) acc[nt] = MFMA16(a, bf[nt][ks], acc[nt]);
        }
#pragma unroll
        for (int nt = 0; nt < 3; nt++) {
            int col = nbase + nt * 16 + l16;
#pragma unroll
            for (int r = 0; r < 4; r++) {
                int node = mt * 16 + q * 4 + r;
                float g = 1.f / (1.f + __expf(-2.f * acc[nt][r]));
                float xv = (float)Xp[(long)node * 192 + col];
                Y[(long)node * 192 + col] = (f16)(xv * g);
            }
        }
    }
}

// ============ K3: t_l = Y@WL (f16) ; x2pre = Y@WR + bl (f16) ============
__global__ __launch_bounds__(256) void sage_lin_kernel(const f16* __restrict__ Y,
                                                       const float* __restrict__ wl,
                                                       const float* __restrict__ wr,
                                                       const float* __restrict__ bl,
                                                       f16* __restrict__ t_l,
                                                       f16* __restrict__ x2) {
    int tid = threadIdx.x, wave = tid >> 6, lane = tid & 63;
    int q = lane >> 4, l16 = lane & 15;
    int g = blockIdx.y;  // 0,1 -> WL ; 2,3 -> WR
    bool isR = (g >= 2);
    const float* W = isR ? wr : wl;
    int cbase = (g & 1) * 64;
    f16x8 bf[4][6];
    float blv[4];
#pragma unroll
    for (int nt = 0; nt < 4; nt++) {
        int col = cbase + nt * 16 + l16;
        blv[nt] = isR ? bl[col] : 0.f;
#pragma unroll
        for (int ks = 0; ks < 6; ks++) {
            int kb = ks * 32 + q * 8;
            f16x8 b;
#pragma unroll
            for (int j = 0; j < 8; j++) {
                int k = kb + j;
                b[j] = (f16)((k < DIN) ? W[k * DH + col] : 0.f);
            }
            bf[nt][ks] = b;
        }
    }
    int stride = gridDim.x * 4;
    for (int mt = blockIdx.x * 4 + wave; mt < 6250; mt += stride) {
        const f16* yrow = Y + (long)(mt * 16 + l16) * 192;
        f32x4 acc[4];
#pragma unroll
        for (int nt = 0; nt < 4; nt++) acc[nt] = (f32x4){0.f, 0.f, 0.f, 0.f};
#pragma unroll
        for (int ks = 0; ks < 6; ks++) {
            f16x8 a = *((const f16x8*)(yrow + ks * 32 + q * 8));
#pragma unroll
            for (int nt = 0; nt < 4; nt++) acc[nt] = MFMA16(a, bf[nt][ks], acc[nt]);
        }
#pragma unroll
        for (int nt = 0; nt < 4; nt++) {
            int col = cbase + nt * 16 + l16;
#pragma unroll
            for (int r = 0; r < 4; r++) {
                int node = mt * 16 + q * 4 + r;
                if (isR)
                    x2[(long)node * DH + col] = (f16)(acc[nt][r] + blv[nt]);
                else
                    t_l[(long)node * DH + col] = (f16)acc[nt][r];
            }
        }
    }
}

// ============ CSR build ============
__global__ void count_kernel(const int* __restrict__ dst, int* __restrict__ cnt) {
    int stride = gridDim.x * blockDim.x;
    for (int e = blockIdx.x * blockDim.x + threadIdx.x; e < N_EDGES; e += stride)
        atomicAdd(&cnt[dst[e]], 1);
}

__global__ __launch_bounds__(1024) void scan_kernel(const int* __restrict__ cnt,
                                                    int* __restrict__ rowptr) {
    __shared__ int wsum[16];
    __shared__ int carry_s;
    int tid = threadIdx.x, lane = tid & 63, wid = tid >> 6;
    if (tid == 0) carry_s = 0;
    __syncthreads();
    for (int base = 0; base < N_NODES; base += 1024) {
        int i = base + tid;
        int v = (i < N_NODES) ? cnt[i] : 0;
        int xv = v;
#pragma unroll
        for (int off = 1; off < 64; off <<= 1) {
            int t = __shfl_up(xv, off);
            if (lane >= off) xv += t;
        }
        if (lane == 63) wsum[wid] = xv;
        __syncthreads();
        if (wid == 0 && lane < 16) {
            int wv = wsum[lane];
#pragma unroll
            for (int off = 1; off < 16; off <<= 1) {
                int t = __shfl_up(wv, off);
                if (lane >= off) wv += t;
            }
            wsum[lane] = wv;
        }
        __syncthreads();
        int off0 = carry_s + (wid ? wsum[wid - 1] : 0);
        if (i < N_NODES) rowptr[i] = off0 + xv - v;
        __syncthreads();
        if (tid == 0) carry_s += wsum[15];
        __syncthreads();
    }
    if (tid == 0) rowptr[N_NODES] = carry_s;
}

__global__ void fill_kernel(const int* __restrict__ src, const int* __restrict__ dst,
                            const int* __restrict__ rowptr, int* __restrict__ fill,
                            int* __restrict__ esrc) {
    int stride = gridDim.x * blockDim.x;
    for (int e = blockIdx.x * blockDim.x + threadIdx.x; e < N_EDGES; e += stride) {
        int d = dst[e];
        int pos = rowptr[d] + atomicAdd(&fill[d], 1);
        esrc[pos] = src[e];
    }
}

// ============ SAGE aggregate: x2 = relu(x2pre + mean(t_l[src])) (f16 in/out) ============
__global__ __launch_bounds__(256) void sage_agg_kernel(const f16* __restrict__ t_l,
                                                       const int* __restrict__ rowptr,
                                                       const int* __restrict__ esrc,
                                                       f16* __restrict__ x2) {
    int wid = threadIdx.x >> 6, lane = threadIdx.x & 63;
    int i = blockIdx.x * 4 + wid;
    int r0 = rowptr[i], r1 = rowptr[i + 1];
    float ax = 0.f, ay = 0.f;
    for (int e0 = r0; e0 < r1; e0 += 64) {
        int cnt = min(64, r1 - e0);
        int sn_v = (lane < cnt) ? esrc[e0 + lane] : 0;
        for (int j = 0; j < cnt; j++) {
            int sn = __shfl(sn_v, j);
            f16x2 p = *((const f16x2*)(t_l + (long)sn * DH) + lane);
            ax += (float)p.x;
            ay += (float)p.y;
        }
    }
    float inv = 1.f / fmaxf((float)(r1 - r0), 1.f);
    f16x2* xp = (f16x2*)(x2 + (long)i * DH) + lane;
    f16x2 pre = *xp;
    f16x2 o;
    o.x = (f16)fmaxf((float)pre.x + ax * inv, 0.f);
    o.y = (f16)fmaxf((float)pre.y + ay * inv, 0.f);
    *xp = o;
}

// ============ K4: h = x2@gw (f16), a_s/a_d row-dots ============
__global__ __launch_bounds__(256) void gat_h_kernel(const f16* __restrict__ x2,
                                                    const float* __restrict__ gw,
                                                    const float* __restrict__ att_s_w,
                                                    const float* __restrict__ att_d_w,
                                                    f16* __restrict__ h,
                                                    float* __restrict__ a_s,
                                                    float* __restrict__ a_d) {
    int tid = threadIdx.x, wave = tid >> 6, lane = tid & 63;
    int q = lane >> 4, l16 = lane & 15;
    f16x8 bf[4][4];
    float asw[4], adw[4];
#pragma unroll
    for (int nt = 0; nt < 4; nt++) {
        int col = nt * 16 + l16;
        asw[nt] = att_s_w[col];
        adw[nt] = att_d_w[col];
#pragma unroll
        for (int ks = 0; ks < 4; ks++) {
            int kb = ks * 32 + q * 8;
            f16x8 b;
#pragma unroll
            for (int j = 0; j < 8; j++) b[j] = (f16)gw[(kb + j) * DG + col];
            bf[nt][ks] = b;
        }
    }
    int stride = gridDim.x * 4;
    for (int mt = blockIdx.x * 4 + wave; mt < 6250; mt += stride) {
        const f16* xr = x2 + (long)(mt * 16 + l16) * DH;
        f32x4 acc[4];
#pragma unroll
        for (int nt = 0; nt < 4; nt++) acc[nt] = (f32x4){0.f, 0.f, 0.f, 0.f};
#pragma unroll
        for (int ks = 0; ks < 4; ks++) {
            f16x8 a = *((const f16x8*)(xr + ks * 32 + q * 8));
#pragma unroll
            for (int nt = 0; nt < 4; nt++) acc[nt] = MFMA16(a, bf[nt][ks], acc[nt]);
        }
#pragma unroll
        for (int r = 0; r < 4; r++) {
            int node = mt * 16 + q * 4 + r;
            float vs = 0.f, vd = 0.f;
#pragma unroll
            for (int nt = 0; nt < 4; nt++) {
                float hv = acc[nt][r];
                h[(long)node * DG + nt * 16 + l16] = (f16)hv;
                vs += hv * asw[nt];
                vd += hv * adw[nt];
            }
#pragma unroll
            for (int off = 1; off < 16; off <<= 1) {
                vs += __shfl_xor(vs, off);
                vd += __shfl_xor(vd, off);
            }
            if (l16 == 0) {
                a_s[node] = vs;
                a_d[node] = vd;
            }
        }
    }
}

// ============ GAT aggregate + bias + relu + Cheb(64->1) + sigmoid ============
__device__ __forceinline__ float leaky02(float v) { return v > 0.f ? v : 0.2f * v; }

__global__ __launch_bounds__(256) void gat_agg_kernel(const f16* __restrict__ h,
                                                      const float* __restrict__ a_s,
                                                      const float* __restrict__ a_d,
                                                      const int* __restrict__ rowptr,
                                                      const int* __restrict__ esrc,
                                                      const float* __restrict__ gat_b,
                                                      const float* __restrict__ cheb_w,
                                                      const float* __restrict__ cheb_b,
                                                      float* __restrict__ out) {
    int wid = threadIdx.x >> 6, lane = threadIdx.x & 63;
    int i = blockIdx.x * 4 + wid;
    int r0 = rowptr[i], r1 = rowptr[i + 1];
    float adi = a_d[i], asi = a_s[i];
    float mx = leaky02(asi + adi);
    for (int e = r0 + lane; e < r1; e += 64)
        mx = fmaxf(mx, leaky02(a_s[esrc[e]] + adi));
#pragma unroll
    for (int off = 32; off > 0; off >>= 1) mx = fmaxf(mx, __shfl_xor(mx, off));
    float ws = __expf(leaky02(asi + adi) - mx);
    float s = ws;
    float acc = ws * (float)h[(long)i * DG + lane];
    for (int e0 = r0; e0 < r1; e0 += 64) {
        int cnt = min(64, r1 - e0);
        int sn_v = (lane < cnt) ? esrc[e0 + lane] : 0;
        float av = (lane < cnt) ? a_s[sn_v] : 0.f;
        for (int j = 0; j < cnt; j++) {
            int sn = __shfl(sn_v, j);
            float w = __expf(leaky02(__shfl(av, j) + adi) - mx);
            s += w;
            acc += w * (float)h[(long)sn * DG + lane];
        }
    }
    float o = fmaxf(acc / s + gat_b[lane], 0.f);
    float z = o * cheb_w[lane];
#pragma unroll
    for (int off = 32; off > 0; off >>= 1) z += __shfl_down(z, off);
    if (lane == 0) out[i] = 1.f / (1.f + __expf(-(z + cheb_b[0])));
}

extern "C" void kernel_launch(void* const* d_in, const int* in_sizes, int n_in,
                              void* d_out, int out_size, void* d_ws, size_t ws_size,
                              hipStream_t stream) {
    const float* x       = (const float*)d_in[0];
    const int*   eidx    = (const int*)d_in[1];
    const float* fb_w1   = (const float*)d_in[2];
    const float* fb_w2   = (const float*)d_in[3];
    const float* sage_wl = (const float*)d_in[4];
    const float* sage_bl = (const float*)d_in[5];
    const float* sage_wr = (const float*)d_in[6];
    const float* gat_w   = (const float*)d_in[7];
    const float* att_src = (const float*)d_in[8];
    const float* att_dst = (const float*)d_in[9];
    const float* gat_b   = (const float*)d_in[10];
    const float* cheb_w  = (const float*)d_in[11];
    const float* cheb_b  = (const float*)d_in[12];

    const int* src = eidx;
    const int* dst = eidx + N_EDGES;

    // workspace (~104 MB with aliasing)
    char* base = (char*)d_ws;
    f16* Xp = (f16*)base;                               //  0    .. 38.4 MB
    f16* H  = (f16*)(base + 38400000);                  // 38.4  .. 57.6 MB
    f16* Y  = (f16*)(base + 57600000);                  // 57.6  .. 96.0 MB
    // t_l aliases Xp (dead after y_kernel); x2 aliases Xp-tail+H (dead after y_kernel)
    f16* t_l = (f16*)base;                              //  0    .. 25.6 MB
    f16* x2  = (f16*)(base + 25600000);                 // 25.6  .. 51.2 MB
    // gat buffers alias Y (dead after sage_lin)
    f16* h   = Y;                                       // 57.6  .. 70.4 MB
    float* a_s = (float*)(base + 70400000);
    float* a_d = a_s + N_NODES;
    // CSR at 96 MB
    int* rowptr = (int*)(base + 96000000);
    int* cnt  = rowptr + (N_NODES + 1);
    int* fill = cnt + N_NODES;
    int* esrc = fill + N_NODES;

    hipMemsetAsync(cnt, 0, 2 * N_NODES * sizeof(int), stream);

    count_kernel<<<1024, 256, 0, stream>>>(dst, cnt);
    scan_kernel<<<1, 1024, 0, stream>>>(cnt, rowptr);
    fill_kernel<<<1024, 256, 0, stream>>>(src, dst, rowptr, fill, esrc);
    xpad_kernel<<<(N_NODES * 48) / 256, 256, 0, stream>>>(x, Xp);
    h_kernel<<<dim3(196, 2), 256, 0, stream>>>(Xp, fb_w1, H);
    y_kernel<<<dim3(196, 4), 256, 0, stream>>>(Xp, H, fb_w2, Y);
    sage_lin_kernel<<<dim3(196, 4), 256, 0, stream>>>(Y, sage_wl, sage_wr, sage_bl, t_l, x2);
    sage_agg_kernel<<<N_NODES / 4, 256, 0, stream>>>(t_l, rowptr, esrc, x2);
    gat_h_kernel<<<392, 256, 0, stream>>>(x2, gat_w, att_src, att_dst, h, a_s, a_d);
    gat_agg_kernel<<<N_NODES / 4, 256, 0, stream>>>(h, a_s, a_d, rowptr, esrc, gat_b,
                                                    cheb_w, cheb_b, (float*)d_out);
}

// Round 5
// 624.158 us; speedup vs baseline: 2.0349x; 1.2269x over previous
//
#include <hip/hip_runtime.h>
#include <hip/hip_bf16.h>

#define N_NODES 100000
#define N_EDGES 1600000
#define DIN 165
#define DHID 82
#define DH 128
#define DG 64

typedef _Float16 f16;
typedef f16 f16x8 __attribute__((ext_vector_type(8)));
typedef f16 f16x4 __attribute__((ext_vector_type(4)));
typedef f16 f16x2 __attribute__((ext_vector_type(2)));
typedef float f32x4 __attribute__((ext_vector_type(4)));

#define MFMA16(a, b, c) __builtin_amdgcn_mfma_f32_16x16x32_f16(a, b, c, 0, 0, 0)

// MFMA 16x16x32 fragment layouts (verified, guide m89/m120):
//   A[m][k]: m = lane&15, k = (lane>>4)*8 + j
//   B[k][n]: n = lane&15, k = (lane>>4)*8 + j
//   D[m][n]: n = lane&15, m = (lane>>4)*4 + reg

// ============ K0: Xp[N,192] f16 = pad(X) ============
__global__ __launch_bounds__(256) void xpad_kernel(const float* __restrict__ x,
                                                   f16* __restrict__ Xp) {
    int gid = blockIdx.x * 256 + threadIdx.x;   // one thread per 4 cols
    int node = gid / 48, g = gid % 48;
    int col0 = g * 4;
    f16x4 o;
#pragma unroll
    for (int j = 0; j < 4; j++) {
        int c = col0 + j;
        o[j] = (f16)((c < DIN) ? x[(long)node * DIN + c] : 0.f);
    }
    *((f16x4*)(Xp + (long)node * 192 + col0)) = o;
}

// ============ K1: H[N,96] f16 = relu(Xp @ W1pad) ============
__global__ __launch_bounds__(256) void h_kernel(const f16* __restrict__ Xp,
                                                const float* __restrict__ w1,
                                                f16* __restrict__ H) {
    int tid = threadIdx.x, wave = tid >> 6, lane = tid & 63;
    int q = lane >> 4, l16 = lane & 15;
    int nbase = blockIdx.y * 48;
    f16x8 bf[3][6];
#pragma unroll
    for (int nt = 0; nt < 3; nt++) {
        int col = nbase + nt * 16 + l16;
#pragma unroll
        for (int ks = 0; ks < 6; ks++) {
            int kb = ks * 32 + q * 8;
            f16x8 b;
#pragma unroll
            for (int j = 0; j < 8; j++) {
                int k = kb + j;
                b[j] = (f16)((k < DIN && col < DHID) ? w1[k * DHID + col] : 0.f);
            }
            bf[nt][ks] = b;
        }
    }
    int stride = gridDim.x * 4;
    for (int mt = blockIdx.x * 4 + wave; mt < 6250; mt += stride) {
        const f16* xr = Xp + (long)(mt * 16 + l16) * 192;
        f32x4 acc[3];
#pragma unroll
        for (int nt = 0; nt < 3; nt++) acc[nt] = (f32x4){0.f, 0.f, 0.f, 0.f};
#pragma unroll
        for (int ks = 0; ks < 6; ks++) {
            f16x8 a = *((const f16x8*)(xr + ks * 32 + q * 8));
#pragma unroll
            for (int nt = 0; nt < 3; nt++) acc[nt] = MFMA16(a, bf[nt][ks], acc[nt]);
        }
#pragma unroll
        for (int nt = 0; nt < 3; nt++) {
            int col = nbase + nt * 16 + l16;
#pragma unroll
            for (int r = 0; r < 4; r++) {
                int node = mt * 16 + q * 4 + r;
                H[(long)node * 96 + col] = (f16)fmaxf(acc[nt][r], 0.f);
            }
        }
    }
}

// ============ K2: Y[N,192] f16 = Xp * sigmoid(2*(H @ W2pad)) ============
__global__ __launch_bounds__(256) void y_kernel(const f16* __restrict__ Xp,
                                                const f16* __restrict__ H,
                                                const float* __restrict__ w2,
                                                f16* __restrict__ Y) {
    int tid = threadIdx.x, wave = tid >> 6, lane = tid & 63;
    int q = lane >> 4, l16 = lane & 15;
    int nbase = blockIdx.y * 48;
    f16x8 bf[3][3];
#pragma unroll
    for (int nt = 0; nt < 3; nt++) {
        int col = nbase + nt * 16 + l16;
#pragma unroll
        for (int ks = 0; ks < 3; ks++) {
            int kb = ks * 32 + q * 8;
            f16x8 b;
#pragma unroll
            for (int j = 0; j < 8; j++) {
                int k = kb + j;
                b[j] = (f16)((k < DHID && col < DIN) ? w2[k * DIN + col] : 0.f);
            }
            bf[nt][ks] = b;
        }
    }
    int stride = gridDim.x * 4;
    for (int mt = blockIdx.x * 4 + wave; mt < 6250; mt += stride) {
        const f16* hr = H + (long)(mt * 16 + l16) * 96;
        f32x4 acc[3];
#pragma unroll
        for (int nt = 0; nt < 3; nt++) acc[nt] = (f32x4){0.f, 0.f, 0.f, 0.f};
#pragma unroll
        for (int ks = 0; ks < 3; ks++) {
            f16x8 a = *((const f16x8*)(hr + ks * 32 + q * 8));
#pragma unroll
            for (int nt = 0; nt < 3; nt++) acc[nt] = MFMA16(a, bf[nt][ks], acc[nt]);
        }
#pragma unroll
        for (int nt = 0; nt < 3; nt++) {
            int col = nbase + nt * 16 + l16;
#pragma unroll
            for (int r = 0; r < 4; r++) {
                int node = mt * 16 + q * 4 + r;
                float g = 1.f / (1.f + __expf(-2.f * acc[nt][r]));
                float xv = (float)Xp[(long)node * 192 + col];
                Y[(long)node * 192 + col] = (f16)(xv * g);
            }
        }
    }
}

// ============ K3: t_l = Y@WL (f16) ; x2pre = Y@WR + bl (f16) ============
__global__ __launch_bounds__(256) void sage_lin_kernel(const f16* __restrict__ Y,
                                                       const float* __restrict__ wl,
                                                       const float* __restrict__ wr,
                                                       const float* __restrict__ bl,
                                                       f16* __restrict__ t_l,
                                                       f16* __restrict__ x2) {
    int tid = threadIdx.x, wave = tid >> 6, lane = tid & 63;
    int q = lane >> 4, l16 = lane & 15;
    int g = blockIdx.y;  // 0,1 -> WL ; 2,3 -> WR
    bool isR = (g >= 2);
    const float* W = isR ? wr : wl;
    int cbase = (g & 1) * 64;
    f16x8 bf[4][6];
    float blv[4];
#pragma unroll
    for (int nt = 0; nt < 4; nt++) {
        int col = cbase + nt * 16 + l16;
        blv[nt] = isR ? bl[col] : 0.f;
#pragma unroll
        for (int ks = 0; ks < 6; ks++) {
            int kb = ks * 32 + q * 8;
            f16x8 b;
#pragma unroll
            for (int j = 0; j < 8; j++) {
                int k = kb + j;
                b[j] = (f16)((k < DIN) ? W[k * DH + col] : 0.f);
            }
            bf[nt][ks] = b;
        }
    }
    int stride = gridDim.x * 4;
    for (int mt = blockIdx.x * 4 + wave; mt < 6250; mt += stride) {
        const f16* yrow = Y + (long)(mt * 16 + l16) * 192;
        f32x4 acc[4];
#pragma unroll
        for (int nt = 0; nt < 4; nt++) acc[nt] = (f32x4){0.f, 0.f, 0.f, 0.f};
#pragma unroll
        for (int ks = 0; ks < 6; ks++) {
            f16x8 a = *((const f16x8*)(yrow + ks * 32 + q * 8));
#pragma unroll
            for (int nt = 0; nt < 4; nt++) acc[nt] = MFMA16(a, bf[nt][ks], acc[nt]);
        }
#pragma unroll
        for (int nt = 0; nt < 4; nt++) {
            int col = cbase + nt * 16 + l16;
#pragma unroll
            for (int r = 0; r < 4; r++) {
                int node = mt * 16 + q * 4 + r;
                if (isR)
                    x2[(long)node * DH + col] = (f16)(acc[nt][r] + blv[nt]);
                else
                    t_l[(long)node * DH + col] = (f16)acc[nt][r];
            }
        }
    }
}

// ============ CSR build ============
__global__ void count_kernel(const int* __restrict__ dst, int* __restrict__ cnt) {
    int stride = gridDim.x * blockDim.x;
    for (int e = blockIdx.x * blockDim.x + threadIdx.x; e < N_EDGES; e += stride)
        atomicAdd(&cnt[dst[e]], 1);
}

// hierarchical scan: 98 parallel block scans -> scan of 98 partials -> offset add
__global__ __launch_bounds__(1024) void scan1_kernel(const int* __restrict__ cnt,
                                                     int* __restrict__ rowptr,
                                                     int* __restrict__ bsum) {
    __shared__ int wsum[16];
    int tid = threadIdx.x, lane = tid & 63, wid = tid >> 6;
    int i = blockIdx.x * 1024 + tid;
    int v = (i < N_NODES) ? cnt[i] : 0;
    int xv = v;
#pragma unroll
    for (int off = 1; off < 64; off <<= 1) {
        int t = __shfl_up(xv, off);
        if (lane >= off) xv += t;
    }
    if (lane == 63) wsum[wid] = xv;
    __syncthreads();
    if (wid == 0 && lane < 16) {
        int wv = wsum[lane];
#pragma unroll
        for (int off = 1; off < 16; off <<= 1) {
            int t = __shfl_up(wv, off);
            if (lane >= off) wv += t;
        }
        wsum[lane] = wv;
    }
    __syncthreads();
    int off0 = wid ? wsum[wid - 1] : 0;
    if (i < N_NODES) rowptr[i] = off0 + xv - v;  // block-local exclusive
    if (tid == 1023) bsum[blockIdx.x] = off0 + xv;
}

__global__ __launch_bounds__(64) void scan2_kernel(const int* __restrict__ bsum,
                                                   int* __restrict__ boff,
                                                   int* __restrict__ rowptr,
                                                   int nblocks) {
    int lane = threadIdx.x;
    int c = 0;
    for (int base = 0; base < nblocks; base += 64) {
        int idx = base + lane;
        int v = (idx < nblocks) ? bsum[idx] : 0;
        int xv = v;
#pragma unroll
        for (int off = 1; off < 64; off <<= 1) {
            int t = __shfl_up(xv, off);
            if (lane >= off) xv += t;
        }
        if (idx < nblocks) boff[idx] = c + xv - v;
        c += __shfl(xv, 63);
    }
    if (lane == 0) rowptr[N_NODES] = c;
}

__global__ __launch_bounds__(1024) void scan3_kernel(int* __restrict__ rowptr,
                                                     const int* __restrict__ boff) {
    int i = blockIdx.x * 1024 + threadIdx.x;
    if (i < N_NODES) rowptr[i] += boff[blockIdx.x];
}

__global__ void fill_kernel(const int* __restrict__ src, const int* __restrict__ dst,
                            const int* __restrict__ rowptr, int* __restrict__ fill,
                            int* __restrict__ esrc) {
    int stride = gridDim.x * blockDim.x;
    for (int e = blockIdx.x * blockDim.x + threadIdx.x; e < N_EDGES; e += stride) {
        int d = dst[e];
        int pos = rowptr[d] + atomicAdd(&fill[d], 1);
        esrc[pos] = src[e];
    }
}

// ============ SAGE aggregate: x2 = relu(x2pre + mean(t_l[src])) (f16 in/out) ============
// quarter-wave: 4 edges/iter, each quarter loads f16x8 (16B) of its edge's row
__global__ __launch_bounds__(256) void sage_agg_kernel(const f16* __restrict__ t_l,
                                                       const int* __restrict__ rowptr,
                                                       const int* __restrict__ esrc,
                                                       f16* __restrict__ x2) {
    int wid = threadIdx.x >> 6, lane = threadIdx.x & 63;
    int i = blockIdx.x * 4 + wid;
    int r0 = rowptr[i], r1 = rowptr[i + 1];
    int quarter = lane >> 4, fq = lane & 15;
    float acc[8];
#pragma unroll
    for (int k = 0; k < 8; k++) acc[k] = 0.f;
    for (int e0 = r0; e0 < r1; e0 += 64) {
        int cnt = min(64, r1 - e0);
        int sn_v = (lane < cnt) ? esrc[e0 + lane] : 0;
        int jmax = (cnt + 3) >> 2;
        for (int j = 0; j < jmax; j++) {
            int idx = 4 * j + quarter;
            int sn = __shfl(sn_v, idx);
            float v = (idx < cnt) ? 1.f : 0.f;
            f16x8 p = *((const f16x8*)(t_l + ((long)sn << 7) + fq * 8));
#pragma unroll
            for (int k = 0; k < 8; k++) acc[k] = fmaf(v, (float)p[k], acc[k]);
        }
    }
#pragma unroll
    for (int k = 0; k < 8; k++) {
        acc[k] += __shfl_xor(acc[k], 16);
        acc[k] += __shfl_xor(acc[k], 32);
    }
    if (quarter == 0) {
        float inv = 1.f / fmaxf((float)(r1 - r0), 1.f);
        f16x8* xp = (f16x8*)(x2 + (long)i * DH + fq * 8);
        f16x8 pre = *xp;
        f16x8 o;
#pragma unroll
        for (int k = 0; k < 8; k++) o[k] = (f16)fmaxf((float)pre[k] + acc[k] * inv, 0.f);
        *xp = o;
    }
}

// ============ K4: h = x2@gw (f16), a_s/a_d row-dots ============
__global__ __launch_bounds__(256) void gat_h_kernel(const f16* __restrict__ x2,
                                                    const float* __restrict__ gw,
                                                    const float* __restrict__ att_s_w,
                                                    const float* __restrict__ att_d_w,
                                                    f16* __restrict__ h,
                                                    float* __restrict__ a_s,
                                                    float* __restrict__ a_d) {
    int tid = threadIdx.x, wave = tid >> 6, lane = tid & 63;
    int q = lane >> 4, l16 = lane & 15;
    f16x8 bf[4][4];
    float asw[4], adw[4];
#pragma unroll
    for (int nt = 0; nt < 4; nt++) {
        int col = nt * 16 + l16;
        asw[nt] = att_s_w[col];
        adw[nt] = att_d_w[col];
#pragma unroll
        for (int ks = 0; ks < 4; ks++) {
            int kb = ks * 32 + q * 8;
            f16x8 b;
#pragma unroll
            for (int j = 0; j < 8; j++) b[j] = (f16)gw[(kb + j) * DG + col];
            bf[nt][ks] = b;
        }
    }
    int stride = gridDim.x * 4;
    for (int mt = blockIdx.x * 4 + wave; mt < 6250; mt += stride) {
        const f16* xr = x2 + (long)(mt * 16 + l16) * DH;
        f32x4 acc[4];
#pragma unroll
        for (int nt = 0; nt < 4; nt++) acc[nt] = (f32x4){0.f, 0.f, 0.f, 0.f};
#pragma unroll
        for (int ks = 0; ks < 4; ks++) {
            f16x8 a = *((const f16x8*)(xr + ks * 32 + q * 8));
#pragma unroll
            for (int nt = 0; nt < 4; nt++) acc[nt] = MFMA16(a, bf[nt][ks], acc[nt]);
        }
#pragma unroll
        for (int r = 0; r < 4; r++) {
            int node = mt * 16 + q * 4 + r;
            float vs = 0.f, vd = 0.f;
#pragma unroll
            for (int nt = 0; nt < 4; nt++) {
                float hv = acc[nt][r];
                h[(long)node * DG + nt * 16 + l16] = (f16)hv;
                vs += hv * asw[nt];
                vd += hv * adw[nt];
            }
#pragma unroll
            for (int off = 1; off < 16; off <<= 1) {
                vs += __shfl_xor(vs, off);
                vd += __shfl_xor(vd, off);
            }
            if (l16 == 0) {
                a_s[node] = vs;
                a_d[node] = vd;
            }
        }
    }
}

// ============ GAT aggregate + bias + relu + Cheb(64->1) + sigmoid ============
// single pass, no max subtraction (logits O(+-15), exp safe in f32; softmax is
// shift-invariant so result identical up to rounding). Lane-parallel exp,
// half-wave 2-edges/iter feature processing.
__device__ __forceinline__ float leaky02(float v) { return v > 0.f ? v : 0.2f * v; }

__global__ __launch_bounds__(256) void gat_agg_kernel(const f16* __restrict__ h,
                                                      const float* __restrict__ a_s,
                                                      const float* __restrict__ a_d,
                                                      const int* __restrict__ rowptr,
                                                      const int* __restrict__ esrc,
                                                      const float* __restrict__ gat_b,
                                                      const float* __restrict__ cheb_w,
                                                      const float* __restrict__ cheb_b,
                                                      float* __restrict__ out) {
    int wid = threadIdx.x >> 6, lane = threadIdx.x & 63;
    int i = blockIdx.x * 4 + wid;
    int r0 = rowptr[i], r1 = rowptr[i + 1];
    int half = lane >> 5, fl = lane & 31;
    float adi = a_d[i];
    float accx = 0.f, accy = 0.f, sv = 0.f;
    for (int e0 = r0; e0 < r1; e0 += 64) {
        int cnt = min(64, r1 - e0);
        int sn_v = (lane < cnt) ? esrc[e0 + lane] : 0;
        float ev = 0.f;
        if (lane < cnt) ev = __expf(leaky02(a_s[sn_v] + adi));
        sv += ev;
        int jmax = (cnt + 1) >> 1;
        for (int j = 0; j < jmax; j++) {
            int idx = 2 * j + half;       // idx==cnt (odd tail) -> ev shfl gives 0
            int sn = __shfl(sn_v, idx);
            float w = __shfl(ev, idx);
            f16x2 p = *((const f16x2*)(h + ((long)sn << 6) + 2 * fl));
            accx = fmaf(w, (float)p.x, accx);
            accy = fmaf(w, (float)p.y, accy);
        }
    }
    // reduce denominator partials across wave
#pragma unroll
    for (int off = 32; off > 0; off >>= 1) sv += __shfl_xor(sv, off);
    // combine half-wave edge partitions (features identical across halves)
    accx += __shfl_xor(accx, 32);
    accy += __shfl_xor(accy, 32);
    // self loop
    float wself = __expf(leaky02(a_s[i] + adi));
    float s = sv + wself;
    f16x2 ph = *((const f16x2*)(h + ((long)i << 6) + 2 * fl));
    accx = fmaf(wself, (float)ph.x, accx);
    accy = fmaf(wself, (float)ph.y, accy);
    float inv = 1.f / s;
    float ox = fmaxf(accx * inv + gat_b[2 * fl], 0.f);
    float oy = fmaxf(accy * inv + gat_b[2 * fl + 1], 0.f);
    float z = ox * cheb_w[2 * fl] + oy * cheb_w[2 * fl + 1];
#pragma unroll
    for (int off = 16; off > 0; off >>= 1) z += __shfl_xor(z, off);
    if (lane == 0) out[i] = 1.f / (1.f + __expf(-(z + cheb_b[0])));
}

extern "C" void kernel_launch(void* const* d_in, const int* in_sizes, int n_in,
                              void* d_out, int out_size, void* d_ws, size_t ws_size,
                              hipStream_t stream) {
    const float* x       = (const float*)d_in[0];
    const int*   eidx    = (const int*)d_in[1];
    const float* fb_w1   = (const float*)d_in[2];
    const float* fb_w2   = (const float*)d_in[3];
    const float* sage_wl = (const float*)d_in[4];
    const float* sage_bl = (const float*)d_in[5];
    const float* sage_wr = (const float*)d_in[6];
    const float* gat_w   = (const float*)d_in[7];
    const float* att_src = (const float*)d_in[8];
    const float* att_dst = (const float*)d_in[9];
    const float* gat_b   = (const float*)d_in[10];
    const float* cheb_w  = (const float*)d_in[11];
    const float* cheb_b  = (const float*)d_in[12];

    const int* src = eidx;
    const int* dst = eidx + N_EDGES;

    // workspace (~104 MB with aliasing)
    char* base = (char*)d_ws;
    f16* Xp = (f16*)base;                               //  0    .. 38.4 MB
    f16* H  = (f16*)(base + 38400000);                  // 38.4  .. 57.6 MB
    f16* Y  = (f16*)(base + 57600000);                  // 57.6  .. 96.0 MB
    f16* t_l = (f16*)base;                              // aliases Xp (dead after y)
    f16* x2  = (f16*)(base + 25600000);                 // aliases Xp-tail+H
    f16* h   = Y;                                       // aliases Y (dead after sage_lin)
    float* a_s = (float*)(base + 70400000);
    float* a_d = a_s + N_NODES;
    int* rowptr = (int*)(base + 96000000);
    int* cnt  = rowptr + (N_NODES + 1);
    int* fill = cnt + N_NODES;
    int* esrc = fill + N_NODES;
    int* bsum = esrc + N_EDGES;        // 98
    int* boff = bsum + 128;            // 98

    const int SCAN_BLOCKS = (N_NODES + 1023) / 1024;   // 98

    hipMemsetAsync(cnt, 0, 2 * N_NODES * sizeof(int), stream);

    count_kernel<<<1024, 256, 0, stream>>>(dst, cnt);
    scan1_kernel<<<SCAN_BLOCKS, 1024, 0, stream>>>(cnt, rowptr, bsum);
    scan2_kernel<<<1, 64, 0, stream>>>(bsum, boff, rowptr, SCAN_BLOCKS);
    scan3_kernel<<<SCAN_BLOCKS, 1024, 0, stream>>>(rowptr, boff);
    fill_kernel<<<1024, 256, 0, stream>>>(src, dst, rowptr, fill, esrc);
    xpad_kernel<<<(N_NODES * 48) / 256, 256, 0, stream>>>(x, Xp);
    h_kernel<<<dim3(196, 2), 256, 0, stream>>>(Xp, fb_w1, H);
    y_kernel<<<dim3(196, 4), 256, 0, stream>>>(Xp, H, fb_w2, Y);
    sage_lin_kernel<<<dim3(196, 4), 256, 0, stream>>>(Y, sage_wl, sage_wr, sage_bl, t_l, x2);
    sage_agg_kernel<<<N_NODES / 4, 256, 0, stream>>>(t_l, rowptr, esrc, x2);
    gat_h_kernel<<<392, 256, 0, stream>>>(x2, gat_w, att_src, att_dst, h, a_s, a_d);
    gat_agg_kernel<<<N_NODES / 4, 256, 0, stream>>>(h, a_s, a_d, rowptr, esrc, gat_b,
                                                    cheb_w, cheb_b, (float*)d_out);
}

// Round 6
// 502.682 us; speedup vs baseline: 2.5267x; 1.2417x over previous
//
#include <hip/hip_runtime.h>
#include <hip/hip_bf16.h>

#define N_NODES 100000
#define N_EDGES 1600000
#define DIN 165
#define DHID 82
#define DH 128
#define DG 64

typedef _Float16 f16;
typedef f16 f16x8 __attribute__((ext_vector_type(8)));
typedef f16 f16x4 __attribute__((ext_vector_type(4)));
typedef f16 f16x2 __attribute__((ext_vector_type(2)));
typedef float f32x4 __attribute__((ext_vector_type(4)));

#define MFMA16(a, b, c) __builtin_amdgcn_mfma_f32_16x16x32_f16(a, b, c, 0, 0, 0)

// MFMA 16x16x32 fragment layouts (verified, guide m89/m120):
//   A[m][k]: m = lane&15, k = (lane>>4)*8 + j
//   B[k][n]: n = lane&15, k = (lane>>4)*8 + j
//   D[m][n]: n = lane&15, m = (lane>>4)*4 + reg

// ============ K0: Xp[N,192] f16 = pad(X) ============
__global__ __launch_bounds__(256) void xpad_kernel(const float* __restrict__ x,
                                                   f16* __restrict__ Xp) {
    int gid = blockIdx.x * 256 + threadIdx.x;   // one thread per 4 cols
    int node = gid / 48, g = gid % 48;
    int col0 = g * 4;
    f16x4 o;
#pragma unroll
    for (int j = 0; j < 4; j++) {
        int c = col0 + j;
        o[j] = (f16)((c < DIN) ? x[(long)node * DIN + c] : 0.f);
    }
    *((f16x4*)(Xp + (long)node * 192 + col0)) = o;
}

// ============ K1: H[N,96] f16 = relu(Xp @ W1pad) ============
// 2 col-groups; XCD-aware decode: all groups of a chunk share an XCD's L2.
__global__ __launch_bounds__(256) void h_kernel(const f16* __restrict__ Xp,
                                                const float* __restrict__ w1,
                                                f16* __restrict__ H) {
    int tid = threadIdx.x, wave = tid >> 6, lane = tid & 63;
    int q = lane >> 4, l16 = lane & 15;
    int blk = blockIdx.x;                       // 384 blocks
    int g = (blk >> 3) & 1;                     // col group
    int chunk = (blk & 7) + 8 * (blk >> 4);     // 0..191, same XCD for both groups
    int nbase = g * 48;
    f16x8 bf[3][6];
#pragma unroll
    for (int nt = 0; nt < 3; nt++) {
        int col = nbase + nt * 16 + l16;
#pragma unroll
        for (int ks = 0; ks < 6; ks++) {
            int kb = ks * 32 + q * 8;
            f16x8 b;
#pragma unroll
            for (int j = 0; j < 8; j++) {
                int k = kb + j;
                b[j] = (f16)((k < DIN && col < DHID) ? w1[k * DHID + col] : 0.f);
            }
            bf[nt][ks] = b;
        }
    }
    for (int mt = chunk * 4 + wave; mt < 6250; mt += 768) {
        const f16* xr = Xp + (long)(mt * 16 + l16) * 192;
        f32x4 acc[3];
#pragma unroll
        for (int nt = 0; nt < 3; nt++) acc[nt] = (f32x4){0.f, 0.f, 0.f, 0.f};
#pragma unroll
        for (int ks = 0; ks < 6; ks++) {
            f16x8 a = *((const f16x8*)(xr + ks * 32 + q * 8));
#pragma unroll
            for (int nt = 0; nt < 3; nt++) acc[nt] = MFMA16(a, bf[nt][ks], acc[nt]);
        }
#pragma unroll
        for (int nt = 0; nt < 3; nt++) {
            int col = nbase + nt * 16 + l16;
#pragma unroll
            for (int r = 0; r < 4; r++) {
                int node = mt * 16 + q * 4 + r;
                H[(long)node * 96 + col] = (f16)fmaxf(acc[nt][r], 0.f);
            }
        }
    }
}

// ============ K2: Y[N,192] f16 = Xp * sigmoid(2*(H @ W2pad)) ============
__global__ __launch_bounds__(256) void y_kernel(const f16* __restrict__ Xp,
                                                const f16* __restrict__ H,
                                                const float* __restrict__ w2,
                                                f16* __restrict__ Y) {
    int tid = threadIdx.x, wave = tid >> 6, lane = tid & 63;
    int q = lane >> 4, l16 = lane & 15;
    int blk = blockIdx.x;                       // 768 blocks
    int g = (blk >> 3) & 3;                     // 4 col groups
    int chunk = (blk & 7) + 8 * (blk >> 5);     // 0..191, same XCD for all 4
    int nbase = g * 48;
    f16x8 bf[3][3];
#pragma unroll
    for (int nt = 0; nt < 3; nt++) {
        int col = nbase + nt * 16 + l16;
#pragma unroll
        for (int ks = 0; ks < 3; ks++) {
            int kb = ks * 32 + q * 8;
            f16x8 b;
#pragma unroll
            for (int j = 0; j < 8; j++) {
                int k = kb + j;
                b[j] = (f16)((k < DHID && col < DIN) ? w2[k * DIN + col] : 0.f);
            }
            bf[nt][ks] = b;
        }
    }
    for (int mt = chunk * 4 + wave; mt < 6250; mt += 768) {
        const f16* hr = H + (long)(mt * 16 + l16) * 96;
        f32x4 acc[3];
#pragma unroll
        for (int nt = 0; nt < 3; nt++) acc[nt] = (f32x4){0.f, 0.f, 0.f, 0.f};
#pragma unroll
        for (int ks = 0; ks < 3; ks++) {
            f16x8 a = *((const f16x8*)(hr + ks * 32 + q * 8));
#pragma unroll
            for (int nt = 0; nt < 3; nt++) acc[nt] = MFMA16(a, bf[nt][ks], acc[nt]);
        }
#pragma unroll
        for (int nt = 0; nt < 3; nt++) {
            int col = nbase + nt * 16 + l16;
#pragma unroll
            for (int r = 0; r < 4; r++) {
                int node = mt * 16 + q * 4 + r;
                float gg = 1.f / (1.f + __expf(-2.f * acc[nt][r]));
                float xv = (float)Xp[(long)node * 192 + col];
                Y[(long)node * 192 + col] = (f16)(xv * gg);
            }
        }
    }
}

// ============ K3: t_l = Y@WL (f16) ; x2pre = Y@WR + bl (f16) ============
__global__ __launch_bounds__(256) void sage_lin_kernel(const f16* __restrict__ Y,
                                                       const float* __restrict__ wl,
                                                       const float* __restrict__ wr,
                                                       const float* __restrict__ bl,
                                                       f16* __restrict__ t_l,
                                                       f16* __restrict__ x2) {
    int tid = threadIdx.x, wave = tid >> 6, lane = tid & 63;
    int q = lane >> 4, l16 = lane & 15;
    int blk = blockIdx.x;                       // 768 blocks
    int g = (blk >> 3) & 3;                     // 0,1 -> WL ; 2,3 -> WR
    int chunk = (blk & 7) + 8 * (blk >> 5);     // 0..191
    bool isR = (g >= 2);
    const float* W = isR ? wr : wl;
    int cbase = (g & 1) * 64;
    f16x8 bf[4][6];
    float blv[4];
#pragma unroll
    for (int nt = 0; nt < 4; nt++) {
        int col = cbase + nt * 16 + l16;
        blv[nt] = isR ? bl[col] : 0.f;
#pragma unroll
        for (int ks = 0; ks < 6; ks++) {
            int kb = ks * 32 + q * 8;
            f16x8 b;
#pragma unroll
            for (int j = 0; j < 8; j++) {
                int k = kb + j;
                b[j] = (f16)((k < DIN) ? W[k * DH + col] : 0.f);
            }
            bf[nt][ks] = b;
        }
    }
    for (int mt = chunk * 4 + wave; mt < 6250; mt += 768) {
        const f16* yrow = Y + (long)(mt * 16 + l16) * 192;
        f32x4 acc[4];
#pragma unroll
        for (int nt = 0; nt < 4; nt++) acc[nt] = (f32x4){0.f, 0.f, 0.f, 0.f};
#pragma unroll
        for (int ks = 0; ks < 6; ks++) {
            f16x8 a = *((const f16x8*)(yrow + ks * 32 + q * 8));
#pragma unroll
            for (int nt = 0; nt < 4; nt++) acc[nt] = MFMA16(a, bf[nt][ks], acc[nt]);
        }
#pragma unroll
        for (int nt = 0; nt < 4; nt++) {
            int col = cbase + nt * 16 + l16;
#pragma unroll
            for (int r = 0; r < 4; r++) {
                int node = mt * 16 + q * 4 + r;
                if (isR)
                    x2[(long)node * DH + col] = (f16)(acc[nt][r] + blv[nt]);
                else
                    t_l[(long)node * DH + col] = (f16)acc[nt][r];
            }
        }
    }
}

// ============ CSR build ============
// rank pass: atomic paid once, old value = within-node rank
__global__ __launch_bounds__(256) void rank_kernel(const int* __restrict__ dst,
                                                   int* __restrict__ cnt,
                                                   int* __restrict__ rank) {
    int e = blockIdx.x * 256 + threadIdx.x;     // one thread per edge
    rank[e] = atomicAdd(&cnt[dst[e]], 1);
}

// hierarchical scan: 98 parallel block scans -> scan of 98 partials -> offset add
__global__ __launch_bounds__(1024) void scan1_kernel(const int* __restrict__ cnt,
                                                     int* __restrict__ rowptr,
                                                     int* __restrict__ bsum) {
    __shared__ int wsum[16];
    int tid = threadIdx.x, lane = tid & 63, wid = tid >> 6;
    int i = blockIdx.x * 1024 + tid;
    int v = (i < N_NODES) ? cnt[i] : 0;
    int xv = v;
#pragma unroll
    for (int off = 1; off < 64; off <<= 1) {
        int t = __shfl_up(xv, off);
        if (lane >= off) xv += t;
    }
    if (lane == 63) wsum[wid] = xv;
    __syncthreads();
    if (wid == 0 && lane < 16) {
        int wv = wsum[lane];
#pragma unroll
        for (int off = 1; off < 16; off <<= 1) {
            int t = __shfl_up(wv, off);
            if (lane >= off) wv += t;
        }
        wsum[lane] = wv;
    }
    __syncthreads();
    int off0 = wid ? wsum[wid - 1] : 0;
    if (i < N_NODES) rowptr[i] = off0 + xv - v;  // block-local exclusive
    if (tid == 1023) bsum[blockIdx.x] = off0 + xv;
}

__global__ __launch_bounds__(64) void scan2_kernel(const int* __restrict__ bsum,
                                                   int* __restrict__ boff,
                                                   int* __restrict__ rowptr,
                                                   int nblocks) {
    int lane = threadIdx.x;
    int c = 0;
    for (int base = 0; base < nblocks; base += 64) {
        int idx = base + lane;
        int v = (idx < nblocks) ? bsum[idx] : 0;
        int xv = v;
#pragma unroll
        for (int off = 1; off < 64; off <<= 1) {
            int t = __shfl_up(xv, off);
            if (lane >= off) xv += t;
        }
        if (idx < nblocks) boff[idx] = c + xv - v;
        c += __shfl(xv, 63);
    }
    if (lane == 0) rowptr[N_NODES] = c;
}

__global__ __launch_bounds__(1024) void scan3_kernel(int* __restrict__ rowptr,
                                                     const int* __restrict__ boff) {
    int i = blockIdx.x * 1024 + threadIdx.x;
    if (i < N_NODES) rowptr[i] += boff[blockIdx.x];
}

// atomic-free fill: pos = rowptr[d] + rank[e]; nontemporal scatter store
__global__ __launch_bounds__(256) void fill_kernel(const int* __restrict__ src,
                                                   const int* __restrict__ dst,
                                                   const int* __restrict__ rank,
                                                   const int* __restrict__ rowptr,
                                                   int* __restrict__ esrc) {
    int e = blockIdx.x * 256 + threadIdx.x;
    int d = dst[e];
    int pos = rowptr[d] + rank[e];
    __builtin_nontemporal_store(src[e], &esrc[pos]);
}

// ============ SAGE aggregate: x2 = relu(x2pre + mean(t_l[src])) (f16 in/out) ============
__global__ __launch_bounds__(256) void sage_agg_kernel(const f16* __restrict__ t_l,
                                                       const int* __restrict__ rowptr,
                                                       const int* __restrict__ esrc,
                                                       f16* __restrict__ x2) {
    int wid = threadIdx.x >> 6, lane = threadIdx.x & 63;
    int i = blockIdx.x * 4 + wid;
    int r0 = rowptr[i], r1 = rowptr[i + 1];
    int quarter = lane >> 4, fq = lane & 15;
    float acc[8];
#pragma unroll
    for (int k = 0; k < 8; k++) acc[k] = 0.f;
    for (int e0 = r0; e0 < r1; e0 += 64) {
        int cnt = min(64, r1 - e0);
        int sn_v = (lane < cnt) ? esrc[e0 + lane] : 0;
        int jmax = (cnt + 3) >> 2;
        for (int j = 0; j < jmax; j++) {
            int idx = 4 * j + quarter;
            int sn = __shfl(sn_v, idx);
            float v = (idx < cnt) ? 1.f : 0.f;
            f16x8 p = *((const f16x8*)(t_l + ((long)sn << 7) + fq * 8));
#pragma unroll
            for (int k = 0; k < 8; k++) acc[k] = fmaf(v, (float)p[k], acc[k]);
        }
    }
#pragma unroll
    for (int k = 0; k < 8; k++) {
        acc[k] += __shfl_xor(acc[k], 16);
        acc[k] += __shfl_xor(acc[k], 32);
    }
    if (quarter == 0) {
        float inv = 1.f / fmaxf((float)(r1 - r0), 1.f);
        f16x8* xp = (f16x8*)(x2 + (long)i * DH + fq * 8);
        f16x8 pre = *xp;
        f16x8 o;
#pragma unroll
        for (int k = 0; k < 8; k++) o[k] = (f16)fmaxf((float)pre[k] + acc[k] * inv, 0.f);
        *xp = o;
    }
}

// ============ K4: h = x2@gw (f16), a_s/a_d row-dots ============
__global__ __launch_bounds__(256) void gat_h_kernel(const f16* __restrict__ x2,
                                                    const float* __restrict__ gw,
                                                    const float* __restrict__ att_s_w,
                                                    const float* __restrict__ att_d_w,
                                                    f16* __restrict__ h,
                                                    float* __restrict__ a_s,
                                                    float* __restrict__ a_d) {
    int tid = threadIdx.x, wave = tid >> 6, lane = tid & 63;
    int q = lane >> 4, l16 = lane & 15;
    f16x8 bf[4][4];
    float asw[4], adw[4];
#pragma unroll
    for (int nt = 0; nt < 4; nt++) {
        int col = nt * 16 + l16;
        asw[nt] = att_s_w[col];
        adw[nt] = att_d_w[col];
#pragma unroll
        for (int ks = 0; ks < 4; ks++) {
            int kb = ks * 32 + q * 8;
            f16x8 b;
#pragma unroll
            for (int j = 0; j < 8; j++) b[j] = (f16)gw[(kb + j) * DG + col];
            bf[nt][ks] = b;
        }
    }
    int stride = gridDim.x * 4;
    for (int mt = blockIdx.x * 4 + wave; mt < 6250; mt += stride) {
        const f16* xr = x2 + (long)(mt * 16 + l16) * DH;
        f32x4 acc[4];
#pragma unroll
        for (int nt = 0; nt < 4; nt++) acc[nt] = (f32x4){0.f, 0.f, 0.f, 0.f};
#pragma unroll
        for (int ks = 0; ks < 4; ks++) {
            f16x8 a = *((const f16x8*)(xr + ks * 32 + q * 8));
#pragma unroll
            for (int nt = 0; nt < 4; nt++) acc[nt] = MFMA16(a, bf[nt][ks], acc[nt]);
        }
#pragma unroll
        for (int r = 0; r < 4; r++) {
            int node = mt * 16 + q * 4 + r;
            float vs = 0.f, vd = 0.f;
#pragma unroll
            for (int nt = 0; nt < 4; nt++) {
                float hv = acc[nt][r];
                h[(long)node * DG + nt * 16 + l16] = (f16)hv;
                vs += hv * asw[nt];
                vd += hv * adw[nt];
            }
#pragma unroll
            for (int off = 1; off < 16; off <<= 1) {
                vs += __shfl_xor(vs, off);
                vd += __shfl_xor(vd, off);
            }
            if (l16 == 0) {
                a_s[node] = vs;
                a_d[node] = vd;
            }
        }
    }
}

// ============ GAT aggregate + bias + relu + Cheb(64->1) + sigmoid ============
__device__ __forceinline__ float leaky02(float v) { return v > 0.f ? v : 0.2f * v; }

__global__ __launch_bounds__(256) void gat_agg_kernel(const f16* __restrict__ h,
                                                      const float* __restrict__ a_s,
                                                      const float* __restrict__ a_d,
                                                      const int* __restrict__ rowptr,
                                                      const int* __restrict__ esrc,
                                                      const float* __restrict__ gat_b,
                                                      const float* __restrict__ cheb_w,
                                                      const float* __restrict__ cheb_b,
                                                      float* __restrict__ out) {
    int wid = threadIdx.x >> 6, lane = threadIdx.x & 63;
    int i = blockIdx.x * 4 + wid;
    int r0 = rowptr[i], r1 = rowptr[i + 1];
    int half = lane >> 5, fl = lane & 31;
    float adi = a_d[i];
    float accx = 0.f, accy = 0.f, sv = 0.f;
    for (int e0 = r0; e0 < r1; e0 += 64) {
        int cnt = min(64, r1 - e0);
        int sn_v = (lane < cnt) ? esrc[e0 + lane] : 0;
        float ev = 0.f;
        if (lane < cnt) ev = __expf(leaky02(a_s[sn_v] + adi));
        sv += ev;
        int jmax = (cnt + 1) >> 1;
        for (int j = 0; j < jmax; j++) {
            int idx = 2 * j + half;
            int sn = __shfl(sn_v, idx);
            float w = __shfl(ev, idx);
            f16x2 p = *((const f16x2*)(h + ((long)sn << 6) + 2 * fl));
            accx = fmaf(w, (float)p.x, accx);
            accy = fmaf(w, (float)p.y, accy);
        }
    }
#pragma unroll
    for (int off = 32; off > 0; off >>= 1) sv += __shfl_xor(sv, off);
    accx += __shfl_xor(accx, 32);
    accy += __shfl_xor(accy, 32);
    float wself = __expf(leaky02(a_s[i] + adi));
    float s = sv + wself;
    f16x2 ph = *((const f16x2*)(h + ((long)i << 6) + 2 * fl));
    accx = fmaf(wself, (float)ph.x, accx);
    accy = fmaf(wself, (float)ph.y, accy);
    float inv = 1.f / s;
    float ox = fmaxf(accx * inv + gat_b[2 * fl], 0.f);
    float oy = fmaxf(accy * inv + gat_b[2 * fl + 1], 0.f);
    float z = ox * cheb_w[2 * fl] + oy * cheb_w[2 * fl + 1];
#pragma unroll
    for (int off = 16; off > 0; off >>= 1) z += __shfl_xor(z, off);
    if (lane == 0) out[i] = 1.f / (1.f + __expf(-(z + cheb_b[0])));
}

extern "C" void kernel_launch(void* const* d_in, const int* in_sizes, int n_in,
                              void* d_out, int out_size, void* d_ws, size_t ws_size,
                              hipStream_t stream) {
    const float* x       = (const float*)d_in[0];
    const int*   eidx    = (const int*)d_in[1];
    const float* fb_w1   = (const float*)d_in[2];
    const float* fb_w2   = (const float*)d_in[3];
    const float* sage_wl = (const float*)d_in[4];
    const float* sage_bl = (const float*)d_in[5];
    const float* sage_wr = (const float*)d_in[6];
    const float* gat_w   = (const float*)d_in[7];
    const float* att_src = (const float*)d_in[8];
    const float* att_dst = (const float*)d_in[9];
    const float* gat_b   = (const float*)d_in[10];
    const float* cheb_w  = (const float*)d_in[11];
    const float* cheb_b  = (const float*)d_in[12];

    const int* src = eidx;
    const int* dst = eidx + N_EDGES;

    // workspace (~110 MB with aliasing)
    char* base = (char*)d_ws;
    f16* Xp = (f16*)base;                               //  0    .. 38.4 MB
    f16* H  = (f16*)(base + 38400000);                  // 38.4  .. 57.6 MB
    f16* Y  = (f16*)(base + 57600000);                  // 57.6  .. 96.0 MB
    f16* t_l = (f16*)base;                              // aliases Xp (dead after y)
    f16* x2  = (f16*)(base + 25600000);                 // aliases Xp-tail+H
    f16* h   = Y;                                       // aliases Y (dead after sage_lin)
    float* a_s = (float*)(base + 70400000);
    float* a_d = a_s + N_NODES;
    int* rowptr = (int*)(base + 96000000);
    int* cnt  = rowptr + (N_NODES + 1);
    int* esrc = cnt + N_NODES;
    int* rank = esrc + N_EDGES;
    int* bsum = rank + N_EDGES;        // 98
    int* boff = bsum + 128;            // 98

    const int SCAN_BLOCKS = (N_NODES + 1023) / 1024;   // 98

    hipMemsetAsync(cnt, 0, N_NODES * sizeof(int), stream);

    rank_kernel<<<N_EDGES / 256, 256, 0, stream>>>(dst, cnt, rank);
    scan1_kernel<<<SCAN_BLOCKS, 1024, 0, stream>>>(cnt, rowptr, bsum);
    scan2_kernel<<<1, 64, 0, stream>>>(bsum, boff, rowptr, SCAN_BLOCKS);
    scan3_kernel<<<SCAN_BLOCKS, 1024, 0, stream>>>(rowptr, boff);
    fill_kernel<<<N_EDGES / 256, 256, 0, stream>>>(src, dst, rank, rowptr, esrc);
    xpad_kernel<<<(N_NODES * 48) / 256, 256, 0, stream>>>(x, Xp);
    h_kernel<<<384, 256, 0, stream>>>(Xp, fb_w1, H);
    y_kernel<<<768, 256, 0, stream>>>(Xp, H, fb_w2, Y);
    sage_lin_kernel<<<768, 256, 0, stream>>>(Y, sage_wl, sage_wr, sage_bl, t_l, x2);
    sage_agg_kernel<<<N_NODES / 4, 256, 0, stream>>>(t_l, rowptr, esrc, x2);
    gat_h_kernel<<<392, 256, 0, stream>>>(x2, gat_w, att_src, att_dst, h, a_s, a_d);
    gat_agg_kernel<<<N_NODES / 4, 256, 0, stream>>>(h, a_s, a_d, rowptr, esrc, gat_b,
                                                    cheb_w, cheb_b, (float*)d_out);
}

// Round 7
// 484.543 us; speedup vs baseline: 2.6213x; 1.0374x over previous
//
#include <hip/hip_runtime.h>
#include <hip/hip_bf16.h>

#define N_NODES 100000
#define N_EDGES 1600000
#define DIN 165
#define DHID 82
#define DH 128
#define DG 64

typedef _Float16 f16;
typedef f16 f16x8 __attribute__((ext_vector_type(8)));
typedef f16 f16x4 __attribute__((ext_vector_type(4)));
typedef f16 f16x2 __attribute__((ext_vector_type(2)));
typedef float f32x4 __attribute__((ext_vector_type(4)));

#define MFMA16(a, b, c) __builtin_amdgcn_mfma_f32_16x16x32_f16(a, b, c, 0, 0, 0)

// MFMA 16x16x32 fragment layouts (verified, guide m89/m120):
//   A[m][k]: m = lane&15, k = (lane>>4)*8 + j
//   B[k][n]: n = lane&15, k = (lane>>4)*8 + j
//   D[m][n]: n = lane&15, m = (lane>>4)*4 + reg

// ============ K1: rank (atomic, throughput-ceiling-bound) + xpad (hidden under it) ============
__global__ __launch_bounds__(256) void rank_xpad_kernel(const float* __restrict__ x,
                                                        f16* __restrict__ Xp,
                                                        const int* __restrict__ dst,
                                                        int* __restrict__ cnt,
                                                        int* __restrict__ rank) {
    int gid = blockIdx.x * 256 + threadIdx.x;
    // atomic issued first; its latency/throughput overlaps the pad work below
    if (gid < N_EDGES) rank[gid] = atomicAdd(&cnt[dst[gid]], 1);
    int node = gid / 48, g = gid % 48;
    int col0 = g * 4;
    f16x4 o;
#pragma unroll
    for (int j = 0; j < 4; j++) {
        int c = col0 + j;
        o[j] = (f16)((c < DIN) ? x[(long)node * DIN + c] : 0.f);
    }
    *((f16x4*)(Xp + (long)node * 192 + col0)) = o;
}

// ============ hierarchical scan ============
__global__ __launch_bounds__(1024) void scan1_kernel(const int* __restrict__ cnt,
                                                     int* __restrict__ rowptr,
                                                     int* __restrict__ bsum) {
    __shared__ int wsum[16];
    int tid = threadIdx.x, lane = tid & 63, wid = tid >> 6;
    int i = blockIdx.x * 1024 + tid;
    int v = (i < N_NODES) ? cnt[i] : 0;
    int xv = v;
#pragma unroll
    for (int off = 1; off < 64; off <<= 1) {
        int t = __shfl_up(xv, off);
        if (lane >= off) xv += t;
    }
    if (lane == 63) wsum[wid] = xv;
    __syncthreads();
    if (wid == 0 && lane < 16) {
        int wv = wsum[lane];
#pragma unroll
        for (int off = 1; off < 16; off <<= 1) {
            int t = __shfl_up(wv, off);
            if (lane >= off) wv += t;
        }
        wsum[lane] = wv;
    }
    __syncthreads();
    int off0 = wid ? wsum[wid - 1] : 0;
    if (i < N_NODES) rowptr[i] = off0 + xv - v;  // block-local exclusive
    if (tid == 1023) bsum[blockIdx.x] = off0 + xv;
}

__global__ __launch_bounds__(64) void scan2_kernel(const int* __restrict__ bsum,
                                                   int* __restrict__ boff,
                                                   int* __restrict__ rowptr,
                                                   int nblocks) {
    int lane = threadIdx.x;
    int c = 0;
    for (int base = 0; base < nblocks; base += 64) {
        int idx = base + lane;
        int v = (idx < nblocks) ? bsum[idx] : 0;
        int xv = v;
#pragma unroll
        for (int off = 1; off < 64; off <<= 1) {
            int t = __shfl_up(xv, off);
            if (lane >= off) xv += t;
        }
        if (idx < nblocks) boff[idx] = c + xv - v;
        c += __shfl(xv, 63);
    }
    if (lane == 0) rowptr[N_NODES] = c;
}

__global__ __launch_bounds__(1024) void scan3_kernel(int* __restrict__ rowptr,
                                                     const int* __restrict__ boff) {
    int i = blockIdx.x * 1024 + threadIdx.x;
    if (i < N_NODES) rowptr[i] += boff[blockIdx.x];
}

// ============ K2: fill prologue (scatter, hidden) + H = relu(Xp@W1) ============
__global__ __launch_bounds__(256) void h_fill_kernel(const f16* __restrict__ Xp,
                                                     const float* __restrict__ w1,
                                                     f16* __restrict__ H,
                                                     const int* __restrict__ src,
                                                     const int* __restrict__ dst,
                                                     const int* __restrict__ rank,
                                                     const int* __restrict__ rowptr,
                                                     int* __restrict__ esrc) {
    int tid = threadIdx.x, wave = tid >> 6, lane = tid & 63;
    // ---- fill prologue: atomic-free CSR scatter (stores are fire-and-forget) ----
    {
        int tg = blockIdx.x * 256 + tid;
        for (int e = tg; e < N_EDGES; e += 384 * 256) {
            int d = dst[e];
            __builtin_nontemporal_store(src[e], &esrc[rowptr[d] + rank[e]]);
        }
    }
    int q = lane >> 4, l16 = lane & 15;
    int blk = blockIdx.x;                       // 384 blocks
    int g = (blk >> 3) & 1;                     // col group
    int chunk = (blk & 7) + 8 * (blk >> 4);     // 0..191, same XCD for both groups
    int nbase = g * 48;
    f16x8 bf[3][6];
#pragma unroll
    for (int nt = 0; nt < 3; nt++) {
        int col = nbase + nt * 16 + l16;
#pragma unroll
        for (int ks = 0; ks < 6; ks++) {
            int kb = ks * 32 + q * 8;
            f16x8 b;
#pragma unroll
            for (int j = 0; j < 8; j++) {
                int k = kb + j;
                b[j] = (f16)((k < DIN && col < DHID) ? w1[k * DHID + col] : 0.f);
            }
            bf[nt][ks] = b;
        }
    }
    for (int mt = chunk * 4 + wave; mt < 6250; mt += 768) {
        const f16* xr = Xp + (long)(mt * 16 + l16) * 192;
        f32x4 acc[3];
#pragma unroll
        for (int nt = 0; nt < 3; nt++) acc[nt] = (f32x4){0.f, 0.f, 0.f, 0.f};
#pragma unroll
        for (int ks = 0; ks < 6; ks++) {
            f16x8 a = *((const f16x8*)(xr + ks * 32 + q * 8));
#pragma unroll
            for (int nt = 0; nt < 3; nt++) acc[nt] = MFMA16(a, bf[nt][ks], acc[nt]);
        }
#pragma unroll
        for (int nt = 0; nt < 3; nt++) {
            int col = nbase + nt * 16 + l16;
#pragma unroll
            for (int r = 0; r < 4; r++) {
                int node = mt * 16 + q * 4 + r;
                H[(long)node * 96 + col] = (f16)fmaxf(acc[nt][r], 0.f);
            }
        }
    }
}

// ============ K3: Y[N,192] f16 = Xp * sigmoid(2*(H @ W2pad)) ============
__global__ __launch_bounds__(256) void y_kernel(const f16* __restrict__ Xp,
                                                const f16* __restrict__ H,
                                                const float* __restrict__ w2,
                                                f16* __restrict__ Y) {
    int tid = threadIdx.x, wave = tid >> 6, lane = tid & 63;
    int q = lane >> 4, l16 = lane & 15;
    int blk = blockIdx.x;                       // 768 blocks
    int g = (blk >> 3) & 3;                     // 4 col groups
    int chunk = (blk & 7) + 8 * (blk >> 5);     // 0..191, same XCD for all 4
    int nbase = g * 48;
    f16x8 bf[3][3];
#pragma unroll
    for (int nt = 0; nt < 3; nt++) {
        int col = nbase + nt * 16 + l16;
#pragma unroll
        for (int ks = 0; ks < 3; ks++) {
            int kb = ks * 32 + q * 8;
            f16x8 b;
#pragma unroll
            for (int j = 0; j < 8; j++) {
                int k = kb + j;
                b[j] = (f16)((k < DHID && col < DIN) ? w2[k * DIN + col] : 0.f);
            }
            bf[nt][ks] = b;
        }
    }
    for (int mt = chunk * 4 + wave; mt < 6250; mt += 768) {
        const f16* hr = H + (long)(mt * 16 + l16) * 96;
        f32x4 acc[3];
#pragma unroll
        for (int nt = 0; nt < 3; nt++) acc[nt] = (f32x4){0.f, 0.f, 0.f, 0.f};
#pragma unroll
        for (int ks = 0; ks < 3; ks++) {
            f16x8 a = *((const f16x8*)(hr + ks * 32 + q * 8));
#pragma unroll
            for (int nt = 0; nt < 3; nt++) acc[nt] = MFMA16(a, bf[nt][ks], acc[nt]);
        }
#pragma unroll
        for (int nt = 0; nt < 3; nt++) {
            int col = nbase + nt * 16 + l16;
#pragma unroll
            for (int r = 0; r < 4; r++) {
                int node = mt * 16 + q * 4 + r;
                float gg = 1.f / (1.f + __expf(-2.f * acc[nt][r]));
                float xv = (float)Xp[(long)node * 192 + col];
                Y[(long)node * 192 + col] = (f16)(xv * gg);
            }
        }
    }
}

// ============ K4: t_l = Y@WL (f16) ; x2pre = Y@WR + bl (f16) ============
__global__ __launch_bounds__(256) void sage_lin_kernel(const f16* __restrict__ Y,
                                                       const float* __restrict__ wl,
                                                       const float* __restrict__ wr,
                                                       const float* __restrict__ bl,
                                                       f16* __restrict__ t_l,
                                                       f16* __restrict__ x2) {
    int tid = threadIdx.x, wave = tid >> 6, lane = tid & 63;
    int q = lane >> 4, l16 = lane & 15;
    int blk = blockIdx.x;                       // 768 blocks
    int g = (blk >> 3) & 3;                     // 0,1 -> WL ; 2,3 -> WR
    int chunk = (blk & 7) + 8 * (blk >> 5);     // 0..191
    bool isR = (g >= 2);
    const float* W = isR ? wr : wl;
    int cbase = (g & 1) * 64;
    f16x8 bf[4][6];
    float blv[4];
#pragma unroll
    for (int nt = 0; nt < 4; nt++) {
        int col = cbase + nt * 16 + l16;
        blv[nt] = isR ? bl[col] : 0.f;
#pragma unroll
        for (int ks = 0; ks < 6; ks++) {
            int kb = ks * 32 + q * 8;
            f16x8 b;
#pragma unroll
            for (int j = 0; j < 8; j++) {
                int k = kb + j;
                b[j] = (f16)((k < DIN) ? W[k * DH + col] : 0.f);
            }
            bf[nt][ks] = b;
        }
    }
    for (int mt = chunk * 4 + wave; mt < 6250; mt += 768) {
        const f16* yrow = Y + (long)(mt * 16 + l16) * 192;
        f32x4 acc[4];
#pragma unroll
        for (int nt = 0; nt < 4; nt++) acc[nt] = (f32x4){0.f, 0.f, 0.f, 0.f};
#pragma unroll
        for (int ks = 0; ks < 6; ks++) {
            f16x8 a = *((const f16x8*)(yrow + ks * 32 + q * 8));
#pragma unroll
            for (int nt = 0; nt < 4; nt++) acc[nt] = MFMA16(a, bf[nt][ks], acc[nt]);
        }
#pragma unroll
        for (int nt = 0; nt < 4; nt++) {
            int col = cbase + nt * 16 + l16;
#pragma unroll
            for (int r = 0; r < 4; r++) {
                int node = mt * 16 + q * 4 + r;
                if (isR)
                    x2[(long)node * DH + col] = (f16)(acc[nt][r] + blv[nt]);
                else
                    t_l[(long)node * DH + col] = (f16)acc[nt][r];
            }
        }
    }
}

// ============ SAGE aggregate: x2 = relu(x2pre + mean(t_l[src])) (f16 in/out) ============
__global__ __launch_bounds__(256) void sage_agg_kernel(const f16* __restrict__ t_l,
                                                       const int* __restrict__ rowptr,
                                                       const int* __restrict__ esrc,
                                                       f16* __restrict__ x2) {
    int wid = threadIdx.x >> 6, lane = threadIdx.x & 63;
    int i = blockIdx.x * 4 + wid;
    int r0 = rowptr[i], r1 = rowptr[i + 1];
    int quarter = lane >> 4, fq = lane & 15;
    float acc[8];
#pragma unroll
    for (int k = 0; k < 8; k++) acc[k] = 0.f;
    for (int e0 = r0; e0 < r1; e0 += 64) {
        int cnt = min(64, r1 - e0);
        int sn_v = (lane < cnt) ? esrc[e0 + lane] : 0;
        int jmax = (cnt + 3) >> 2;
        for (int j = 0; j < jmax; j++) {
            int idx = 4 * j + quarter;
            int sn = __shfl(sn_v, idx);
            float v = (idx < cnt) ? 1.f : 0.f;
            f16x8 p = *((const f16x8*)(t_l + ((long)sn << 7) + fq * 8));
#pragma unroll
            for (int k = 0; k < 8; k++) acc[k] = fmaf(v, (float)p[k], acc[k]);
        }
    }
#pragma unroll
    for (int k = 0; k < 8; k++) {
        acc[k] += __shfl_xor(acc[k], 16);
        acc[k] += __shfl_xor(acc[k], 32);
    }
    if (quarter == 0) {
        float inv = 1.f / fmaxf((float)(r1 - r0), 1.f);
        f16x8* xp = (f16x8*)(x2 + (long)i * DH + fq * 8);
        f16x8 pre = *xp;
        f16x8 o;
#pragma unroll
        for (int k = 0; k < 8; k++) o[k] = (f16)fmaxf((float)pre[k] + acc[k] * inv, 0.f);
        *xp = o;
    }
}

// ============ K5: h = x2@gw (f16), a_s/a_d row-dots ============
__global__ __launch_bounds__(256) void gat_h_kernel(const f16* __restrict__ x2,
                                                    const float* __restrict__ gw,
                                                    const float* __restrict__ att_s_w,
                                                    const float* __restrict__ att_d_w,
                                                    f16* __restrict__ h,
                                                    float* __restrict__ a_s,
                                                    float* __restrict__ a_d) {
    int tid = threadIdx.x, wave = tid >> 6, lane = tid & 63;
    int q = lane >> 4, l16 = lane & 15;
    f16x8 bf[4][4];
    float asw[4], adw[4];
#pragma unroll
    for (int nt = 0; nt < 4; nt++) {
        int col = nt * 16 + l16;
        asw[nt] = att_s_w[col];
        adw[nt] = att_d_w[col];
#pragma unroll
        for (int ks = 0; ks < 4; ks++) {
            int kb = ks * 32 + q * 8;
            f16x8 b;
#pragma unroll
            for (int j = 0; j < 8; j++) b[j] = (f16)gw[(kb + j) * DG + col];
            bf[nt][ks] = b;
        }
    }
    int stride = gridDim.x * 4;
    for (int mt = blockIdx.x * 4 + wave; mt < 6250; mt += stride) {
        const f16* xr = x2 + (long)(mt * 16 + l16) * DH;
        f32x4 acc[4];
#pragma unroll
        for (int nt = 0; nt < 4; nt++) acc[nt] = (f32x4){0.f, 0.f, 0.f, 0.f};
#pragma unroll
        for (int ks = 0; ks < 4; ks++) {
            f16x8 a = *((const f16x8*)(xr + ks * 32 + q * 8));
#pragma unroll
            for (int nt = 0; nt < 4; nt++) acc[nt] = MFMA16(a, bf[nt][ks], acc[nt]);
        }
#pragma unroll
        for (int r = 0; r < 4; r++) {
            int node = mt * 16 + q * 4 + r;
            float vs = 0.f, vd = 0.f;
#pragma unroll
            for (int nt = 0; nt < 4; nt++) {
                float hv = acc[nt][r];
                h[(long)node * DG + nt * 16 + l16] = (f16)hv;
                vs += hv * asw[nt];
                vd += hv * adw[nt];
            }
#pragma unroll
            for (int off = 1; off < 16; off <<= 1) {
                vs += __shfl_xor(vs, off);
                vd += __shfl_xor(vd, off);
            }
            if (l16 == 0) {
                a_s[node] = vs;
                a_d[node] = vd;
            }
        }
    }
}

// ============ GAT aggregate + bias + relu + Cheb(64->1) + sigmoid ============
// quarter-wave: 4 edges/iter, 16 lanes x f16x4 per 128B row; no-max softmax.
__device__ __forceinline__ float leaky02(float v) { return v > 0.f ? v : 0.2f * v; }

__global__ __launch_bounds__(256) void gat_agg_kernel(const f16* __restrict__ h,
                                                      const float* __restrict__ a_s,
                                                      const float* __restrict__ a_d,
                                                      const int* __restrict__ rowptr,
                                                      const int* __restrict__ esrc,
                                                      const float* __restrict__ gat_b,
                                                      const float* __restrict__ cheb_w,
                                                      const float* __restrict__ cheb_b,
                                                      float* __restrict__ out) {
    int wid = threadIdx.x >> 6, lane = threadIdx.x & 63;
    int i = blockIdx.x * 4 + wid;
    int r0 = rowptr[i], r1 = rowptr[i + 1];
    int quarter = lane >> 4, fq = lane & 15;
    float adi = a_d[i];
    float acc[4] = {0.f, 0.f, 0.f, 0.f};
    float sv = 0.f;
    for (int e0 = r0; e0 < r1; e0 += 64) {
        int cnt = min(64, r1 - e0);
        int sn_v = (lane < cnt) ? esrc[e0 + lane] : 0;
        float ev = 0.f;
        if (lane < cnt) ev = __expf(leaky02(a_s[sn_v] + adi));
        sv += ev;
        int jmax = (cnt + 3) >> 2;
        for (int j = 0; j < jmax; j++) {
            int idx = 4 * j + quarter;           // idx>=cnt -> ev shfl gives 0
            int sn = __shfl(sn_v, idx);
            float w = __shfl(ev, idx);
            f16x4 p = *((const f16x4*)(h + ((long)sn << 6) + fq * 4));
#pragma unroll
            for (int k = 0; k < 4; k++) acc[k] = fmaf(w, (float)p[k], acc[k]);
        }
    }
#pragma unroll
    for (int off = 32; off > 0; off >>= 1) sv += __shfl_xor(sv, off);
#pragma unroll
    for (int k = 0; k < 4; k++) {
        acc[k] += __shfl_xor(acc[k], 16);
        acc[k] += __shfl_xor(acc[k], 32);
    }
    if (quarter == 0) {
        float wself = __expf(leaky02(a_s[i] + adi));
        float s = sv + wself;
        f16x4 ph = *((const f16x4*)(h + ((long)i << 6) + fq * 4));
        float4 gb = ((const float4*)gat_b)[fq];
        float4 cw = ((const float4*)cheb_w)[fq];
        float gbv[4] = {gb.x, gb.y, gb.z, gb.w};
        float cwv[4] = {cw.x, cw.y, cw.z, cw.w};
        float inv = 1.f / s;
        float z = 0.f;
#pragma unroll
        for (int k = 0; k < 4; k++) {
            float o = fmaxf(fmaf(wself, (float)ph[k], acc[k]) * inv + gbv[k], 0.f);
            z = fmaf(o, cwv[k], z);
        }
#pragma unroll
        for (int off = 8; off > 0; off >>= 1) z += __shfl_xor(z, off);
        if (fq == 0) out[i] = 1.f / (1.f + __expf(-(z + cheb_b[0])));
    }
}

extern "C" void kernel_launch(void* const* d_in, const int* in_sizes, int n_in,
                              void* d_out, int out_size, void* d_ws, size_t ws_size,
                              hipStream_t stream) {
    const float* x       = (const float*)d_in[0];
    const int*   eidx    = (const int*)d_in[1];
    const float* fb_w1   = (const float*)d_in[2];
    const float* fb_w2   = (const float*)d_in[3];
    const float* sage_wl = (const float*)d_in[4];
    const float* sage_bl = (const float*)d_in[5];
    const float* sage_wr = (const float*)d_in[6];
    const float* gat_w   = (const float*)d_in[7];
    const float* att_src = (const float*)d_in[8];
    const float* att_dst = (const float*)d_in[9];
    const float* gat_b   = (const float*)d_in[10];
    const float* cheb_w  = (const float*)d_in[11];
    const float* cheb_b  = (const float*)d_in[12];

    const int* src = eidx;
    const int* dst = eidx + N_EDGES;

    // workspace (~110 MB with aliasing)
    char* base = (char*)d_ws;
    f16* Xp = (f16*)base;                               //  0    .. 38.4 MB
    f16* H  = (f16*)(base + 38400000);                  // 38.4  .. 57.6 MB
    f16* Y  = (f16*)(base + 57600000);                  // 57.6  .. 96.0 MB
    f16* t_l = (f16*)base;                              // aliases Xp (dead after y)
    f16* x2  = (f16*)(base + 25600000);                 // aliases Xp-tail+H
    f16* h   = Y;                                       // aliases Y (dead after sage_lin)
    float* a_s = (float*)(base + 70400000);
    float* a_d = a_s + N_NODES;
    int* rowptr = (int*)(base + 96000000);
    int* cnt  = rowptr + (N_NODES + 1);
    int* esrc = cnt + N_NODES;
    int* rank = esrc + N_EDGES;
    int* bsum = rank + N_EDGES;        // 98
    int* boff = bsum + 128;            // 98

    const int SCAN_BLOCKS = (N_NODES + 1023) / 1024;   // 98

    hipMemsetAsync(cnt, 0, N_NODES * sizeof(int), stream);

    rank_xpad_kernel<<<(N_NODES * 48) / 256, 256, 0, stream>>>(x, Xp, dst, cnt, rank);
    scan1_kernel<<<SCAN_BLOCKS, 1024, 0, stream>>>(cnt, rowptr, bsum);
    scan2_kernel<<<1, 64, 0, stream>>>(bsum, boff, rowptr, SCAN_BLOCKS);
    scan3_kernel<<<SCAN_BLOCKS, 1024, 0, stream>>>(rowptr, boff);
    h_fill_kernel<<<384, 256, 0, stream>>>(Xp, fb_w1, H, src, dst, rank, rowptr, esrc);
    y_kernel<<<768, 256, 0, stream>>>(Xp, H, fb_w2, Y);
    sage_lin_kernel<<<768, 256, 0, stream>>>(Y, sage_wl, sage_wr, sage_bl, t_l, x2);
    sage_agg_kernel<<<N_NODES / 4, 256, 0, stream>>>(t_l, rowptr, esrc, x2);
    gat_h_kernel<<<392, 256, 0, stream>>>(x2, gat_w, att_src, att_dst, h, a_s, a_d);
    gat_agg_kernel<<<N_NODES / 4, 256, 0, stream>>>(h, a_s, a_d, rowptr, esrc, gat_b,
                                                    cheb_w, cheb_b, (float*)d_out);
}